// Round 6
// baseline (1132.245 us; speedup 1.0000x reference)
//
#include <hip/hip_runtime.h>
#include <hip/hip_bf16.h>
#include <cstddef>

#define N_NODES 100000
#define N_EDGES 3200000
#define N_GRAPHS 2048
#define IN_FEATS 64
#define HIDDEN 128
#define EXTRA 8

#define SCAN_CHUNK 1024
#define NB_CHUNKS ((N_NODES + SCAN_CHUNK - 1) / SCAN_CHUNK)  // 98

// counting-sort parameters
#define R_BINS 16000                 // 64000 B LDS histogram
#define NPASS 7                      // 7 * 16000 >= 100000
#define G_SORT 256
#define CHUNK (N_EDGES / G_SORT)     // 12500

typedef unsigned short bf16_t;
typedef short bfx8 __attribute__((ext_vector_type(8)));
typedef float f32x4 __attribute__((ext_vector_type(4)));

__device__ __forceinline__ float selu_f(float x) {
    const float scale = 1.0507009873554805f;
    const float alpha = 1.6732632423543772f;
    return x > 0.f ? scale * x : scale * alpha * (__expf(x) - 1.f);
}
__device__ __forceinline__ float bf2f(unsigned short u) {
    union { unsigned int i; float f; } c; c.i = ((unsigned int)u) << 16; return c.f;
}
__device__ __forceinline__ unsigned short f2bf(float f) {
    union { float f; unsigned int i; } c; c.f = f;
    unsigned int lsb = (c.i >> 16) & 1;
    c.i += 0x7fffu + lsb;                 // round to nearest even
    return (unsigned short)(c.i >> 16);
}

// ============ counting-sort CSR build (no global atomics) ============

__global__ __launch_bounds__(512) void histo_kernel(const int* __restrict__ src,
                                                    const int* __restrict__ dst,
                                                    unsigned char* __restrict__ h_src,
                                                    unsigned char* __restrict__ h_dst) {
    __shared__ unsigned int hist[R_BINS];
    const int b = blockIdx.x, t = threadIdx.x;
    const int e0 = b * CHUNK;
#pragma unroll
    for (int ph = 0; ph < 2; ++ph) {
        const int4* key4 = (const int4*)((ph ? src : dst) + e0);
        unsigned char* hout = (ph ? h_src : h_dst) + (size_t)b * N_NODES;
        for (int p = 0; p < NPASS; ++p) {
            const int r0 = p * R_BINS;
            const int rend = min(R_BINS, N_NODES - r0);
            for (int i = t; i < R_BINS; i += 512) hist[i] = 0;
            __syncthreads();
            for (int i = t; i < CHUNK / 4; i += 512) {
                int4 k = key4[i];
                unsigned int x;
                x = (unsigned)(k.x - r0); if (x < (unsigned)R_BINS) atomicAdd(&hist[x], 1u);
                x = (unsigned)(k.y - r0); if (x < (unsigned)R_BINS) atomicAdd(&hist[x], 1u);
                x = (unsigned)(k.z - r0); if (x < (unsigned)R_BINS) atomicAdd(&hist[x], 1u);
                x = (unsigned)(k.w - r0); if (x < (unsigned)R_BINS) atomicAdd(&hist[x], 1u);
            }
            __syncthreads();
            for (int i = t; i < rend; i += 512) hout[r0 + i] = (unsigned char)hist[i];
            __syncthreads();
        }
    }
}

__global__ __launch_bounds__(256) void colsum_kernel(const unsigned char* __restrict__ h_src,
                                                     int* __restrict__ outdeg) {
    int bin = blockIdx.x * 256 + threadIdx.x;
    if (bin >= N_NODES) return;
    int s = 0;
#pragma unroll 8
    for (int b = 0; b < G_SORT; ++b) s += h_src[(size_t)b * N_NODES + bin];
    outdeg[bin] = s;
}

__global__ __launch_bounds__(256) void scanp_kernel(unsigned char* __restrict__ h_dst,
                                                    int* __restrict__ indeg) {
    int bin = blockIdx.x * 256 + threadIdx.x;
    if (bin >= N_NODES) return;
    int run = 0;
#pragma unroll 8
    for (int b = 0; b < G_SORT; ++b) {
        size_t off = (size_t)b * N_NODES + bin;
        int v = h_dst[off];
        h_dst[off] = (unsigned char)run;
        run += v;
    }
    indeg[bin] = run;
}

__global__ __launch_bounds__(512) void sortT_kernel(const int* __restrict__ src,
                                                    const int* __restrict__ dst,
                                                    const unsigned char* __restrict__ h_dst,
                                                    const int* __restrict__ rowptr,
                                                    int* __restrict__ csr_src) {
    __shared__ unsigned int cnt[R_BINS];
    const int b = blockIdx.x, t = threadIdx.x;
    const int e0 = b * CHUNK;
    const int4* d4p = (const int4*)(dst + e0);
    const int4* s4p = (const int4*)(src + e0);
    const unsigned char* hrow = h_dst + (size_t)b * N_NODES;
    for (int p = 0; p < NPASS; ++p) {
        const int r0 = p * R_BINS;
        const unsigned int rend = (unsigned)min(R_BINS, N_NODES - r0);
        for (int i = t; i < (int)rend; i += 512)
            cnt[i] = (unsigned)rowptr[r0 + i] + (unsigned)hrow[r0 + i];
        __syncthreads();
        for (int i = t; i < CHUNK / 4; i += 512) {
            int4 d = d4p[i];
            int4 s = s4p[i];
            unsigned int x;
            x = (unsigned)(d.x - r0); if (x < rend) { unsigned slot = atomicAdd(&cnt[x], 1u); csr_src[slot] = s.x; }
            x = (unsigned)(d.y - r0); if (x < rend) { unsigned slot = atomicAdd(&cnt[x], 1u); csr_src[slot] = s.y; }
            x = (unsigned)(d.z - r0); if (x < rend) { unsigned slot = atomicAdd(&cnt[x], 1u); csr_src[slot] = s.z; }
            x = (unsigned)(d.w - r0); if (x < rend) { unsigned slot = atomicAdd(&cnt[x], 1u); csr_src[slot] = s.w; }
        }
        __syncthreads();
    }
}

// ============ norms, rowptr scan, weights, features ============

__global__ __launch_bounds__(256) void norm_kernel(const int* __restrict__ outdeg,
                                                   const int* __restrict__ indeg,
                                                   float* __restrict__ nsrc,
                                                   float* __restrict__ ndst) {
    int i = blockIdx.x * 256 + threadIdx.x;
    if (i < N_NODES) {
        nsrc[i] = rsqrtf(fmaxf((float)outdeg[i], 1.f));
        ndst[i] = rsqrtf(fmaxf((float)indeg[i], 1.f));
    }
}

__global__ __launch_bounds__(256) void scanA(const int* __restrict__ indeg,
                                             int* __restrict__ partials) {
    __shared__ int red[4];
    const int b = blockIdx.x, t = threadIdx.x;
    int base = b * SCAN_CHUNK + t * 4;
    int s = 0;
#pragma unroll
    for (int k = 0; k < 4; ++k) { int i = base + k; if (i < N_NODES) s += indeg[i]; }
    for (int off = 32; off; off >>= 1) s += __shfl_down(s, off);
    if ((t & 63) == 0) red[t >> 6] = s;
    __syncthreads();
    if (t == 0) partials[b] = red[0] + red[1] + red[2] + red[3];
}

__global__ __launch_bounds__(128) void scanB(int* __restrict__ partials,
                                             int* __restrict__ rowptr) {
    __shared__ int s[128];
    const int t = threadIdx.x;
    int v = (t < NB_CHUNKS) ? partials[t] : 0;
    s[t] = v;
    __syncthreads();
    for (int off = 1; off < 128; off <<= 1) {
        int u = (t >= off) ? s[t - off] : 0;
        __syncthreads();
        s[t] += u;
        __syncthreads();
    }
    if (t < NB_CHUNKS) partials[t] = s[t] - v;   // exclusive
    if (t == 127) rowptr[N_NODES] = s[127];
}

__global__ __launch_bounds__(256) void scanC(const int* __restrict__ indeg,
                                             const int* __restrict__ partials,
                                             int* __restrict__ rowptr) {
    __shared__ int ts[256];
    const int b = blockIdx.x, t = threadIdx.x;
    int base = b * SCAN_CHUNK + t * 4;
    int v[4];
    int s = 0;
#pragma unroll
    for (int k = 0; k < 4; ++k) { int i = base + k; v[k] = (i < N_NODES) ? indeg[i] : 0; s += v[k]; }
    ts[t] = s;
    __syncthreads();
    for (int off = 1; off < 256; off <<= 1) {
        int u = (t >= off) ? ts[t - off] : 0;
        __syncthreads();
        ts[t] += u;
        __syncthreads();
    }
    int excl = ts[t] - s + partials[b];
#pragma unroll
    for (int k = 0; k < 4; ++k) {
        int i = base + k;
        if (i < N_NODES) rowptr[i] = excl;
        excl += v[k];
    }
}

__global__ __launch_bounds__(256) void wprep_kernel(const float* __restrict__ W,
                                                    bf16_t* __restrict__ Wt, int K) {
    int i = blockIdx.x * 256 + threadIdx.x;
    if (i >= 128 * K) return;
    int n = i / K, k = i - n * K;
    Wt[i] = f2bf(W[k * 128 + n]);
}

__global__ __launch_bounds__(256) void prescale_kernel(const float* __restrict__ x,
                                                       const float* __restrict__ nsrc,
                                                       bf16_t* __restrict__ xb) {
    int i = blockIdx.x * 256 + threadIdx.x;
    const int total = N_NODES * (IN_FEATS / 4);
    if (i >= total) return;
    int node = i >> 4;                       // IN_FEATS/4 == 16
    float nm = nsrc[node];
    float4 v = ((const float4*)x)[i];
    ushort4 o;
    o.x = f2bf(v.x * nm); o.y = f2bf(v.y * nm);
    o.z = f2bf(v.z * nm); o.w = f2bf(v.w * nm);
    ((ushort4*)xb)[i] = o;
}

// ============ panel gather: one XCD per 16-feature panel ============
// hP/outP layout: [8][N_NODES][16] bf16. blockIdx.x & 7 selects panel ->
// round-robin dispatch pins each panel to one XCD; its 3.2 MB panel stays
// L2-resident (avg indeg 32 -> ~97% hit).
template <bool SCALE_OUT>
__global__ __launch_bounds__(256) void gatherP_kernel(const bf16_t* __restrict__ hP,
                                                      const int* __restrict__ rowptr,
                                                      const int* __restrict__ csr_src,
                                                      const float* __restrict__ ndst,
                                                      const float* __restrict__ nsrc,
                                                      const float* __restrict__ bias,
                                                      bf16_t* __restrict__ outP) {
    const int p = blockIdx.x & 7;
    const int node = (((blockIdx.x >> 3) * 256) + threadIdx.x) >> 6;  // 4 nodes/block
    if (node >= N_NODES) return;
    const int l = threadIdx.x & 63;
    const int g = l >> 3;                 // edge-group 0..7
    const int k = l & 7;                  // feat-pair 0..7
    const bf16_t* bp = hP + (size_t)p * N_NODES * 16;
    const int r0 = rowptr[node], r1 = rowptr[node + 1];
    float a0 = 0.f, a1 = 0.f;
    for (int base = r0; base < r1; base += 64) {
        const int nb = min(64, r1 - base);
        int myidx = csr_src[base + min(l, nb - 1)];
#pragma unroll
        for (int j = 0; j < 64; j += 8) {
            if (j >= nb) break;
            int e = j + g;
            int s = __shfl(myidx, min(e, nb - 1));
            if (e < nb) {
                ushort2 u = *(const ushort2*)(bp + (size_t)s * 16 + k * 2);
                a0 += bf2f(u.x); a1 += bf2f(u.y);
            }
        }
    }
    a0 += __shfl_xor(a0, 8);  a1 += __shfl_xor(a1, 8);
    a0 += __shfl_xor(a0, 16); a1 += __shfl_xor(a1, 16);
    a0 += __shfl_xor(a0, 32); a1 += __shfl_xor(a1, 32);
    if (g == 0) {
        const float nm = ndst[node];
        const int f0 = p * 16 + k * 2;
        float v0 = selu_f(a0 * nm + bias[f0]);
        float v1 = selu_f(a1 * nm + bias[f0 + 1]);
        if (SCALE_OUT) { float sc = nsrc[node]; v0 *= sc; v1 *= sc; }
        ushort2 o; o.x = f2bf(v0); o.y = f2bf(v1);
        *(ushort2*)(outP + ((size_t)p * N_NODES + node) * 16 + k * 2) = o;
    }
}

// ============ MFMA node matmul: raw m = h @ Wt, panel-major output ============
// A_PANEL: input h is panel-major [8][N][16]; else row-major [N][K].
template <int K, bool A_PANEL>
__global__ __launch_bounds__(256) void node_matmul_mfma(const bf16_t* __restrict__ Hb,
                                                        const bf16_t* __restrict__ Wt,
                                                        bf16_t* __restrict__ outP) {
    __shared__ char sW[128 * K * 2];
    const int t = threadIdx.x;

    for (int fb = t * 16; fb < 128 * K * 2; fb += 256 * 16) {
        bfx8 v = *(const bfx8*)((const char*)Wt + fb);
        int n = fb / (2 * K);
        *(bfx8*)(sW + (fb ^ ((n & 7) << 4))) = v;
    }
    __syncthreads();

    const int wv = t >> 6;
    const int l  = t & 63;
    const int m  = l & 15;
    const int kb = l >> 4;
    const int row0 = blockIdx.x * 64 + wv * 16;

    int arow = row0 + m;
    if (arow > N_NODES - 1) arow = N_NODES - 1;

    f32x4 acc[8];
#pragma unroll
    for (int f = 0; f < 8; ++f) acc[f] = (f32x4){0.f, 0.f, 0.f, 0.f};

#pragma unroll
    for (int kc = 0; kc < K / 32; ++kc) {
        const char* ap;
        if (A_PANEL) {
            int fb = kc * 64 + kb * 16;          // byte offset within 256-B feature row
            int pp = fb >> 5;
            ap = (const char*)Hb + ((size_t)pp * N_NODES + arow) * 32 + (fb & 31);
        } else {
            ap = (const char*)(Hb + (size_t)arow * K) + kc * 64 + kb * 16;
        }
        bfx8 a = *(const bfx8*)ap;
#pragma unroll
        for (int f = 0; f < 8; ++f) {
            int n = f * 16 + m;
            int off = n * (2 * K) + kc * 64 + kb * 16;
            off ^= (n & 7) << 4;
            bfx8 b = *(const bfx8*)(sW + off);
            acc[f] = __builtin_amdgcn_mfma_f32_16x16x32_bf16(a, b, acc[f], 0, 0, 0);
        }
    }

    // D[m'][n]: node m' = row0 + kb*4 + j ; feat n = f*16 + m -> panel f, elem m
#pragma unroll
    for (int f = 0; f < 8; ++f) {
        bf16_t* op = outP + (size_t)f * N_NODES * 16 + m;
#pragma unroll
        for (int j = 0; j < 4; ++j) {
            int node = row0 + kb * 4 + j;
            if (node < N_NODES) op[(size_t)node * 16] = f2bf(acc[f][j]);
        }
    }
}

// ============ pool (panel-major input) + MLP head ============
__global__ __launch_bounds__(256) void pool_kernel(const bf16_t* __restrict__ hP,
                                                   const int* __restrict__ gid,
                                                   float* __restrict__ emb,
                                                   float* __restrict__ cnt) {
    const int lane = threadIdx.x & 63;
    const int wid = (blockIdx.x * 256 + threadIdx.x) >> 6;
    const int n0 = wid * 64;
    if (n0 >= N_NODES) return;
    const int nend = (n0 + 64 < N_NODES) ? n0 + 64 : N_NODES;
    const bf16_t* bp = hP + (size_t)(lane >> 3) * N_NODES * 16 + (lane & 7) * 2;
    int cur = gid[n0];
    float ax = 0.f, ay = 0.f, run = 0.f;
    for (int n = n0; n < nend; ++n) {
        int g = gid[n];
        if (g != cur) {
            atomicAdd(&emb[(size_t)cur * HIDDEN + lane * 2], ax);
            atomicAdd(&emb[(size_t)cur * HIDDEN + lane * 2 + 1], ay);
            if (lane == 0) atomicAdd(&cnt[cur], run);
            cur = g; ax = 0.f; ay = 0.f; run = 0.f;
        }
        ushort2 u = *(const ushort2*)(bp + (size_t)n * 16);
        ax += bf2f(u.x); ay += bf2f(u.y);
        run += 1.f;
    }
    atomicAdd(&emb[(size_t)cur * HIDDEN + lane * 2], ax);
    atomicAdd(&emb[(size_t)cur * HIDDEN + lane * 2 + 1], ay);
    if (lane == 0) atomicAdd(&cnt[cur], run);
}

__global__ __launch_bounds__(256) void mlp_kernel(const float* __restrict__ emb,
                                                  const float* __restrict__ cnt,
                                                  const float* __restrict__ fg,
                                                  const float* __restrict__ M1, const float* __restrict__ c1,
                                                  const float* __restrict__ M2, const float* __restrict__ c2,
                                                  const float* __restrict__ M3, const float* __restrict__ c3,
                                                  float* __restrict__ out) {
    const int g = blockIdx.x;
    const int t = threadIdx.x;
    __shared__ float z[HIDDEN + EXTRA];
    __shared__ float z1[2 * HIDDEN];
    __shared__ float z2[HIDDEN];
    if (t < HIDDEN) {
        float c = fmaxf(cnt[g], 1.f);
        z[t] = emb[(size_t)g * HIDDEN + t] / c;
    } else if (t < HIDDEN + EXTRA) {
        z[t] = fg[g * EXTRA + (t - HIDDEN)];
    }
    __syncthreads();
    {
        float s = c1[t];
        for (int k = 0; k < HIDDEN + EXTRA; ++k) s += z[k] * M1[k * (2 * HIDDEN) + t];
        z1[t] = selu_f(s);
    }
    __syncthreads();
    if (t < HIDDEN) {
        float s = c2[t];
        for (int k = 0; k < 2 * HIDDEN; ++k) s += z1[k] * M2[k * HIDDEN + t];
        z2[t] = selu_f(s);
    }
    __syncthreads();
    if (t < 64) {
        float s = z2[t] * M3[t] + z2[t + 64] * M3[t + 64];
#pragma unroll
        for (int off = 32; off; off >>= 1) s += __shfl_down(s, off);
        if (t == 0) out[g] = s + c3[0];
    }
}

extern "C" void kernel_launch(void* const* d_in, const int* in_sizes, int n_in,
                              void* d_out, int out_size, void* d_ws, size_t ws_size,
                              hipStream_t stream) {
    const float* feats_node  = (const float*)d_in[0];
    const float* feats_graph = (const float*)d_in[1];
    const int*   src         = (const int*)d_in[2];
    const int*   dst         = (const int*)d_in[3];
    const int*   gid         = (const int*)d_in[4];
    const float* W1 = (const float*)d_in[5];
    const float* b1 = (const float*)d_in[6];
    const float* W2 = (const float*)d_in[7];
    const float* b2 = (const float*)d_in[8];
    const float* W3 = (const float*)d_in[9];
    const float* b3 = (const float*)d_in[10];
    const float* M1 = (const float*)d_in[11];
    const float* c1 = (const float*)d_in[12];
    const float* M2 = (const float*)d_in[13];
    const float* c2 = (const float*)d_in[14];
    const float* M3 = (const float*)d_in[15];
    const float* c3 = (const float*)d_in[16];
    float* out = (float*)d_out;

    char* ws = (char*)d_ws;
    int* indeg   = (int*)ws;  ws += (size_t)N_NODES * sizeof(int);
    int* outdeg  = (int*)ws;  ws += (size_t)N_NODES * sizeof(int);
    int* rowptr  = (int*)ws;  ws += (size_t)(N_NODES + 4) * sizeof(int);
    int* partials= (int*)ws;  ws += 128 * sizeof(int);
    float* norm_src = (float*)ws; ws += (size_t)N_NODES * sizeof(float);
    float* norm_dst = (float*)ws; ws += (size_t)N_NODES * sizeof(float);
    bf16_t* Wt1 = (bf16_t*)ws; ws += (size_t)128 * IN_FEATS * sizeof(bf16_t);
    bf16_t* Wt2 = (bf16_t*)ws; ws += (size_t)128 * HIDDEN * sizeof(bf16_t);
    bf16_t* Wt3 = (bf16_t*)ws; ws += (size_t)128 * HIDDEN * sizeof(bf16_t);
    int* csr_src = (int*)ws;  ws += (size_t)N_EDGES * sizeof(int);
    bf16_t* bufB = (bf16_t*)ws; ws += (size_t)N_NODES * HIDDEN * sizeof(bf16_t);
    // union 1: h_dst (alive histo..sortT) / bufA (alive after sortT)
    unsigned char* h_dst = (unsigned char*)ws;
    bf16_t* bufA = (bf16_t*)ws;
    ws += (size_t)G_SORT * N_NODES;                                  // 25.6 MB
    // union 2: h_src (alive histo..colsum) / xb + emb + cnt
    unsigned char* h_src = (unsigned char*)ws;
    bf16_t* xb   = (bf16_t*)ws;
    float* emb   = (float*)(ws + (size_t)N_NODES * IN_FEATS * sizeof(bf16_t));
    float* cnt   = emb + (size_t)N_GRAPHS * HIDDEN;
    ws += (size_t)G_SORT * N_NODES;                                  // 25.6 MB

    // ---- CSR build (counting sort, no global atomics) ----
    histo_kernel<<<G_SORT, 512, 0, stream>>>(src, dst, h_src, h_dst);
    colsum_kernel<<<(N_NODES + 255) / 256, 256, 0, stream>>>(h_src, outdeg);
    scanp_kernel<<<(N_NODES + 255) / 256, 256, 0, stream>>>(h_dst, indeg);
    scanA<<<NB_CHUNKS, 256, 0, stream>>>(indeg, partials);
    scanB<<<1, 128, 0, stream>>>(partials, rowptr);
    scanC<<<NB_CHUNKS, 256, 0, stream>>>(indeg, partials, rowptr);
    norm_kernel<<<(N_NODES + 255) / 256, 256, 0, stream>>>(outdeg, indeg, norm_src, norm_dst);
    sortT_kernel<<<G_SORT, 512, 0, stream>>>(src, dst, h_dst, rowptr, csr_src);

    // ---- weight prep + prescale (xb overlays h_src: dead after colsum) ----
    wprep_kernel<<<(128 * IN_FEATS + 255) / 256, 256, 0, stream>>>(W1, Wt1, IN_FEATS);
    wprep_kernel<<<(128 * HIDDEN + 255) / 256, 256, 0, stream>>>(W2, Wt2, HIDDEN);
    wprep_kernel<<<(128 * HIDDEN + 255) / 256, 256, 0, stream>>>(W3, Wt3, HIDDEN);
    prescale_kernel<<<(N_NODES * (IN_FEATS / 4) + 255) / 256, 256, 0, stream>>>(feats_node, norm_src, xb);

    const int mm_grid = (N_NODES + 63) / 64;
    const int gp_grid = 8 * ((N_NODES + 3) / 4);   // 8 panels x 25000 node-chunks

    // layer 1: matmul-first (xb row-major 64 -> panel-major 128), then panel gather
    node_matmul_mfma<IN_FEATS, false><<<mm_grid, 256, 0, stream>>>(xb, Wt1, bufB);
    gatherP_kernel<true><<<gp_grid, 256, 0, stream>>>(bufB, rowptr, csr_src, norm_dst, norm_src, b1, bufA);

    // layer 2
    node_matmul_mfma<HIDDEN, true><<<mm_grid, 256, 0, stream>>>(bufA, Wt2, bufB);
    gatherP_kernel<true><<<gp_grid, 256, 0, stream>>>(bufB, rowptr, csr_src, norm_dst, norm_src, b2, bufA);

    // layer 3 (no nsrc on output; feeds pooling)
    node_matmul_mfma<HIDDEN, true><<<mm_grid, 256, 0, stream>>>(bufA, Wt3, bufB);
    gatherP_kernel<false><<<gp_grid, 256, 0, stream>>>(bufB, rowptr, csr_src, norm_dst, norm_src, b3, bufA);

    // readout + MLP
    hipMemsetAsync(emb, 0, ((size_t)N_GRAPHS * HIDDEN + N_GRAPHS) * sizeof(float), stream);
    const int n_waves = (N_NODES + 63) / 64;
    pool_kernel<<<(n_waves + 3) / 4, 256, 0, stream>>>(bufA, gid, emb, cnt);
    mlp_kernel<<<N_GRAPHS, 256, 0, stream>>>(emb, cnt, feats_graph,
                                             M1, c1, M2, c2, M3, c3, out);
}

// Round 7
// 917.703 us; speedup vs baseline: 1.2338x; 1.2338x over previous
//
#include <hip/hip_runtime.h>
#include <hip/hip_bf16.h>
#include <cstddef>

#define N_NODES 100000
#define N_EDGES 3200000
#define N_GRAPHS 2048
#define IN_FEATS 64
#define HIDDEN 128
#define EXTRA 8

#define SCAN_CHUNK 1024
#define NB_CHUNKS ((N_NODES + SCAN_CHUNK - 1) / SCAN_CHUNK)  // 98

// counting-sort parameters
#define R_BINS 16000                 // 64000 B LDS histogram
#define NPASS 7                      // 7 * 16000 >= 100000
#define G_SORT 256
#define CHUNK (N_EDGES / G_SORT)     // 12500

typedef unsigned short bf16_t;
typedef short bfx8 __attribute__((ext_vector_type(8)));
typedef float f32x4 __attribute__((ext_vector_type(4)));

__device__ __forceinline__ float selu_f(float x) {
    const float scale = 1.0507009873554805f;
    const float alpha = 1.6732632423543772f;
    return x > 0.f ? scale * x : scale * alpha * (__expf(x) - 1.f);
}
__device__ __forceinline__ float bf2f(unsigned short u) {
    union { unsigned int i; float f; } c; c.i = ((unsigned int)u) << 16; return c.f;
}
__device__ __forceinline__ unsigned short f2bf(float f) {
    union { float f; unsigned int i; } c; c.f = f;
    unsigned int lsb = (c.i >> 16) & 1;
    c.i += 0x7fffu + lsb;                 // round to nearest even
    return (unsigned short)(c.i >> 16);
}

// ============ counting-sort CSR build (no global atomics) ============

__global__ __launch_bounds__(512) void histo_kernel(const int* __restrict__ src,
                                                    const int* __restrict__ dst,
                                                    unsigned char* __restrict__ h_src,
                                                    unsigned char* __restrict__ h_dst) {
    __shared__ unsigned int hist[R_BINS];
    const int b = blockIdx.x, t = threadIdx.x;
    const int e0 = b * CHUNK;
#pragma unroll
    for (int ph = 0; ph < 2; ++ph) {
        const int4* key4 = (const int4*)((ph ? src : dst) + e0);
        unsigned char* hout = (ph ? h_src : h_dst) + (size_t)b * N_NODES;
        for (int p = 0; p < NPASS; ++p) {
            const int r0 = p * R_BINS;
            const int rend = min(R_BINS, N_NODES - r0);
            for (int i = t; i < R_BINS; i += 512) hist[i] = 0;
            __syncthreads();
            for (int i = t; i < CHUNK / 4; i += 512) {
                int4 k = key4[i];
                unsigned int x;
                x = (unsigned)(k.x - r0); if (x < (unsigned)R_BINS) atomicAdd(&hist[x], 1u);
                x = (unsigned)(k.y - r0); if (x < (unsigned)R_BINS) atomicAdd(&hist[x], 1u);
                x = (unsigned)(k.z - r0); if (x < (unsigned)R_BINS) atomicAdd(&hist[x], 1u);
                x = (unsigned)(k.w - r0); if (x < (unsigned)R_BINS) atomicAdd(&hist[x], 1u);
            }
            __syncthreads();
            for (int i = t; i < rend; i += 512) hout[r0 + i] = (unsigned char)hist[i];
            __syncthreads();
        }
    }
}

__global__ __launch_bounds__(256) void colsum_kernel(const unsigned char* __restrict__ h_src,
                                                     int* __restrict__ outdeg) {
    int bin = blockIdx.x * 256 + threadIdx.x;
    if (bin >= N_NODES) return;
    int s = 0;
#pragma unroll 8
    for (int b = 0; b < G_SORT; ++b) s += h_src[(size_t)b * N_NODES + bin];
    outdeg[bin] = s;
}

__global__ __launch_bounds__(256) void scanp_kernel(unsigned char* __restrict__ h_dst,
                                                    int* __restrict__ indeg) {
    int bin = blockIdx.x * 256 + threadIdx.x;
    if (bin >= N_NODES) return;
    int run = 0;
#pragma unroll 8
    for (int b = 0; b < G_SORT; ++b) {
        size_t off = (size_t)b * N_NODES + bin;
        int v = h_dst[off];
        h_dst[off] = (unsigned char)run;
        run += v;
    }
    indeg[bin] = run;
}

__global__ __launch_bounds__(512) void sortT_kernel(const int* __restrict__ src,
                                                    const int* __restrict__ dst,
                                                    const unsigned char* __restrict__ h_dst,
                                                    const int* __restrict__ rowptr,
                                                    int* __restrict__ csr_src) {
    __shared__ unsigned int cnt[R_BINS];
    const int b = blockIdx.x, t = threadIdx.x;
    const int e0 = b * CHUNK;
    const int4* d4p = (const int4*)(dst + e0);
    const int4* s4p = (const int4*)(src + e0);
    const unsigned char* hrow = h_dst + (size_t)b * N_NODES;
    for (int p = 0; p < NPASS; ++p) {
        const int r0 = p * R_BINS;
        const unsigned int rend = (unsigned)min(R_BINS, N_NODES - r0);
        for (int i = t; i < (int)rend; i += 512)
            cnt[i] = (unsigned)rowptr[r0 + i] + (unsigned)hrow[r0 + i];
        __syncthreads();
        for (int i = t; i < CHUNK / 4; i += 512) {
            int4 d = d4p[i];
            int4 s = s4p[i];
            unsigned int x;
            x = (unsigned)(d.x - r0); if (x < rend) { unsigned slot = atomicAdd(&cnt[x], 1u); csr_src[slot] = s.x; }
            x = (unsigned)(d.y - r0); if (x < rend) { unsigned slot = atomicAdd(&cnt[x], 1u); csr_src[slot] = s.y; }
            x = (unsigned)(d.z - r0); if (x < rend) { unsigned slot = atomicAdd(&cnt[x], 1u); csr_src[slot] = s.z; }
            x = (unsigned)(d.w - r0); if (x < rend) { unsigned slot = atomicAdd(&cnt[x], 1u); csr_src[slot] = s.w; }
        }
        __syncthreads();
    }
}

// ============ norms, rowptr scan, weights, features ============

__global__ __launch_bounds__(256) void norm_kernel(const int* __restrict__ outdeg,
                                                   const int* __restrict__ indeg,
                                                   float* __restrict__ nsrc,
                                                   float* __restrict__ ndst) {
    int i = blockIdx.x * 256 + threadIdx.x;
    if (i < N_NODES) {
        nsrc[i] = rsqrtf(fmaxf((float)outdeg[i], 1.f));
        ndst[i] = rsqrtf(fmaxf((float)indeg[i], 1.f));
    }
}

__global__ __launch_bounds__(256) void scanA(const int* __restrict__ indeg,
                                             int* __restrict__ partials) {
    __shared__ int red[4];
    const int b = blockIdx.x, t = threadIdx.x;
    int base = b * SCAN_CHUNK + t * 4;
    int s = 0;
#pragma unroll
    for (int k = 0; k < 4; ++k) { int i = base + k; if (i < N_NODES) s += indeg[i]; }
    for (int off = 32; off; off >>= 1) s += __shfl_down(s, off);
    if ((t & 63) == 0) red[t >> 6] = s;
    __syncthreads();
    if (t == 0) partials[b] = red[0] + red[1] + red[2] + red[3];
}

__global__ __launch_bounds__(128) void scanB(int* __restrict__ partials,
                                             int* __restrict__ rowptr) {
    __shared__ int s[128];
    const int t = threadIdx.x;
    int v = (t < NB_CHUNKS) ? partials[t] : 0;
    s[t] = v;
    __syncthreads();
    for (int off = 1; off < 128; off <<= 1) {
        int u = (t >= off) ? s[t - off] : 0;
        __syncthreads();
        s[t] += u;
        __syncthreads();
    }
    if (t < NB_CHUNKS) partials[t] = s[t] - v;   // exclusive
    if (t == 127) rowptr[N_NODES] = s[127];
}

__global__ __launch_bounds__(256) void scanC(const int* __restrict__ indeg,
                                             const int* __restrict__ partials,
                                             int* __restrict__ rowptr) {
    __shared__ int ts[256];
    const int b = blockIdx.x, t = threadIdx.x;
    int base = b * SCAN_CHUNK + t * 4;
    int v[4];
    int s = 0;
#pragma unroll
    for (int k = 0; k < 4; ++k) { int i = base + k; v[k] = (i < N_NODES) ? indeg[i] : 0; s += v[k]; }
    ts[t] = s;
    __syncthreads();
    for (int off = 1; off < 256; off <<= 1) {
        int u = (t >= off) ? ts[t - off] : 0;
        __syncthreads();
        ts[t] += u;
        __syncthreads();
    }
    int excl = ts[t] - s + partials[b];
#pragma unroll
    for (int k = 0; k < 4; ++k) {
        int i = base + k;
        if (i < N_NODES) rowptr[i] = excl;
        excl += v[k];
    }
}

__global__ __launch_bounds__(256) void wprep_kernel(const float* __restrict__ W,
                                                    bf16_t* __restrict__ Wt, int K) {
    int i = blockIdx.x * 256 + threadIdx.x;
    if (i >= 128 * K) return;
    int n = i / K, k = i - n * K;
    Wt[i] = f2bf(W[k * 128 + n]);
}

__global__ __launch_bounds__(256) void prescale_kernel(const float* __restrict__ x,
                                                       const float* __restrict__ nsrc,
                                                       bf16_t* __restrict__ xb) {
    int i = blockIdx.x * 256 + threadIdx.x;
    const int total = N_NODES * (IN_FEATS / 4);
    if (i >= total) return;
    int node = i >> 4;                       // IN_FEATS/4 == 16
    float nm = nsrc[node];
    float4 v = ((const float4*)x)[i];
    ushort4 o;
    o.x = f2bf(v.x * nm); o.y = f2bf(v.y * nm);
    o.z = f2bf(v.z * nm); o.w = f2bf(v.w * nm);
    ((ushort4*)xb)[i] = o;
}

// ============ panel gather v2: no shuffles in the edge loop ============
// hP/outP layout: [8][N_NODES][16] bf16. blockIdx.x & 7 = panel (XCD-pinned
// via round-robin dispatch; 3.2 MB panel stays L2-resident — verified r6:
// FETCH 512->68 MB). Wave = 2 nodes; per node: 8 edge-slots x 4 feat-quads.
// Lane computes its own edge index (no ds_bpermute), loads csr (coalesced
// 4 B) + row quad (8 B saddr-form), accumulates; one 3-level shfl_xor tree
// per node after the loop.
template <bool SCALE_OUT>
__global__ __launch_bounds__(256) void gatherP_kernel(const bf16_t* __restrict__ hP,
                                                      const int* __restrict__ rowptr,
                                                      const int* __restrict__ csr_src,
                                                      const float* __restrict__ ndst,
                                                      const float* __restrict__ nsrc,
                                                      const float* __restrict__ bias,
                                                      bf16_t* __restrict__ outP) {
    const int p = blockIdx.x & 7;
    const int l = threadIdx.x & 63;
    const int node = ((blockIdx.x >> 3) << 3) + ((threadIdx.x >> 6) << 1) + (l >> 5);
    const int es = (l >> 2) & 7;          // edge slot 0..7
    const int q  = l & 3;                 // feat quad 0..3
    const char* bp = (const char*)(hP + (size_t)p * (N_NODES * 16) + q * 4);

    const int r1 = rowptr[node + 1];
    float a0 = 0.f, a1 = 0.f, a2 = 0.f, a3 = 0.f;
    for (int e = rowptr[node] + es; e < r1; e += 8) {
        int s = csr_src[e];
        unsigned off = (unsigned)s << 5;          // s * 32 bytes
        ushort4 u = *(const ushort4*)(bp + off);
        a0 += bf2f(u.x); a1 += bf2f(u.y); a2 += bf2f(u.z); a3 += bf2f(u.w);
    }
    // reduce over 8 edge slots (strided by 4 lanes): xor 4, 8, 16
#pragma unroll
    for (int m = 4; m <= 16; m <<= 1) {
        a0 += __shfl_xor(a0, m); a1 += __shfl_xor(a1, m);
        a2 += __shfl_xor(a2, m); a3 += __shfl_xor(a3, m);
    }
    if (es == 0) {
        const float nm = ndst[node];
        const int f0 = p * 16 + q * 4;
        float v0 = selu_f(a0 * nm + bias[f0]);
        float v1 = selu_f(a1 * nm + bias[f0 + 1]);
        float v2 = selu_f(a2 * nm + bias[f0 + 2]);
        float v3 = selu_f(a3 * nm + bias[f0 + 3]);
        if (SCALE_OUT) { float sc = nsrc[node]; v0 *= sc; v1 *= sc; v2 *= sc; v3 *= sc; }
        ushort4 o; o.x = f2bf(v0); o.y = f2bf(v1); o.z = f2bf(v2); o.w = f2bf(v3);
        *(ushort4*)(outP + ((size_t)p * N_NODES + node) * 16 + q * 4) = o;
    }
}

// ============ MFMA node matmul: raw m = h @ Wt, panel-major output ============
// A_PANEL: input h is panel-major [8][N][16]; else row-major [N][K].
template <int K, bool A_PANEL>
__global__ __launch_bounds__(256) void node_matmul_mfma(const bf16_t* __restrict__ Hb,
                                                        const bf16_t* __restrict__ Wt,
                                                        bf16_t* __restrict__ outP) {
    __shared__ char sW[128 * K * 2];
    const int t = threadIdx.x;

    for (int fb = t * 16; fb < 128 * K * 2; fb += 256 * 16) {
        bfx8 v = *(const bfx8*)((const char*)Wt + fb);
        int n = fb / (2 * K);
        *(bfx8*)(sW + (fb ^ ((n & 7) << 4))) = v;
    }
    __syncthreads();

    const int wv = t >> 6;
    const int l  = t & 63;
    const int m  = l & 15;
    const int kb = l >> 4;
    const int row0 = blockIdx.x * 64 + wv * 16;

    int arow = row0 + m;
    if (arow > N_NODES - 1) arow = N_NODES - 1;

    f32x4 acc[8];
#pragma unroll
    for (int f = 0; f < 8; ++f) acc[f] = (f32x4){0.f, 0.f, 0.f, 0.f};

#pragma unroll
    for (int kc = 0; kc < K / 32; ++kc) {
        const char* ap;
        if (A_PANEL) {
            int fb = kc * 64 + kb * 16;          // byte offset within 256-B feature row
            int pp = fb >> 5;
            ap = (const char*)Hb + ((size_t)pp * N_NODES + arow) * 32 + (fb & 31);
        } else {
            ap = (const char*)(Hb + (size_t)arow * K) + kc * 64 + kb * 16;
        }
        bfx8 a = *(const bfx8*)ap;
#pragma unroll
        for (int f = 0; f < 8; ++f) {
            int n = f * 16 + m;
            int off = n * (2 * K) + kc * 64 + kb * 16;
            off ^= (n & 7) << 4;
            bfx8 b = *(const bfx8*)(sW + off);
            acc[f] = __builtin_amdgcn_mfma_f32_16x16x32_bf16(a, b, acc[f], 0, 0, 0);
        }
    }

    // D[m'][n]: node m' = row0 + kb*4 + j ; feat n = f*16 + m -> panel f, elem m
#pragma unroll
    for (int f = 0; f < 8; ++f) {
        bf16_t* op = outP + (size_t)f * N_NODES * 16 + m;
#pragma unroll
        for (int j = 0; j < 4; ++j) {
            int node = row0 + kb * 4 + j;
            if (node < N_NODES) op[(size_t)node * 16] = f2bf(acc[f][j]);
        }
    }
}

// ============ pool (panel-major input) + MLP head ============
__global__ __launch_bounds__(256) void pool_kernel(const bf16_t* __restrict__ hP,
                                                   const int* __restrict__ gid,
                                                   float* __restrict__ emb,
                                                   float* __restrict__ cnt) {
    const int lane = threadIdx.x & 63;
    const int wid = (blockIdx.x * 256 + threadIdx.x) >> 6;
    const int n0 = wid * 64;
    if (n0 >= N_NODES) return;
    const int nend = (n0 + 64 < N_NODES) ? n0 + 64 : N_NODES;
    const bf16_t* bp = hP + (size_t)(lane >> 3) * N_NODES * 16 + (lane & 7) * 2;
    int cur = gid[n0];
    float ax = 0.f, ay = 0.f, run = 0.f;
    for (int n = n0; n < nend; ++n) {
        int g = gid[n];
        if (g != cur) {
            atomicAdd(&emb[(size_t)cur * HIDDEN + lane * 2], ax);
            atomicAdd(&emb[(size_t)cur * HIDDEN + lane * 2 + 1], ay);
            if (lane == 0) atomicAdd(&cnt[cur], run);
            cur = g; ax = 0.f; ay = 0.f; run = 0.f;
        }
        ushort2 u = *(const ushort2*)(bp + (size_t)n * 16);
        ax += bf2f(u.x); ay += bf2f(u.y);
        run += 1.f;
    }
    atomicAdd(&emb[(size_t)cur * HIDDEN + lane * 2], ax);
    atomicAdd(&emb[(size_t)cur * HIDDEN + lane * 2 + 1], ay);
    if (lane == 0) atomicAdd(&cnt[cur], run);
}

__global__ __launch_bounds__(256) void mlp_kernel(const float* __restrict__ emb,
                                                  const float* __restrict__ cnt,
                                                  const float* __restrict__ fg,
                                                  const float* __restrict__ M1, const float* __restrict__ c1,
                                                  const float* __restrict__ M2, const float* __restrict__ c2,
                                                  const float* __restrict__ M3, const float* __restrict__ c3,
                                                  float* __restrict__ out) {
    const int g = blockIdx.x;
    const int t = threadIdx.x;
    __shared__ float z[HIDDEN + EXTRA];
    __shared__ float z1[2 * HIDDEN];
    __shared__ float z2[HIDDEN];
    if (t < HIDDEN) {
        float c = fmaxf(cnt[g], 1.f);
        z[t] = emb[(size_t)g * HIDDEN + t] / c;
    } else if (t < HIDDEN + EXTRA) {
        z[t] = fg[g * EXTRA + (t - HIDDEN)];
    }
    __syncthreads();
    {
        float s = c1[t];
        for (int k = 0; k < HIDDEN + EXTRA; ++k) s += z[k] * M1[k * (2 * HIDDEN) + t];
        z1[t] = selu_f(s);
    }
    __syncthreads();
    if (t < HIDDEN) {
        float s = c2[t];
        for (int k = 0; k < 2 * HIDDEN; ++k) s += z1[k] * M2[k * HIDDEN + t];
        z2[t] = selu_f(s);
    }
    __syncthreads();
    if (t < 64) {
        float s = z2[t] * M3[t] + z2[t + 64] * M3[t + 64];
#pragma unroll
        for (int off = 32; off; off >>= 1) s += __shfl_down(s, off);
        if (t == 0) out[g] = s + c3[0];
    }
}

extern "C" void kernel_launch(void* const* d_in, const int* in_sizes, int n_in,
                              void* d_out, int out_size, void* d_ws, size_t ws_size,
                              hipStream_t stream) {
    const float* feats_node  = (const float*)d_in[0];
    const float* feats_graph = (const float*)d_in[1];
    const int*   src         = (const int*)d_in[2];
    const int*   dst         = (const int*)d_in[3];
    const int*   gid         = (const int*)d_in[4];
    const float* W1 = (const float*)d_in[5];
    const float* b1 = (const float*)d_in[6];
    const float* W2 = (const float*)d_in[7];
    const float* b2 = (const float*)d_in[8];
    const float* W3 = (const float*)d_in[9];
    const float* b3 = (const float*)d_in[10];
    const float* M1 = (const float*)d_in[11];
    const float* c1 = (const float*)d_in[12];
    const float* M2 = (const float*)d_in[13];
    const float* c2 = (const float*)d_in[14];
    const float* M3 = (const float*)d_in[15];
    const float* c3 = (const float*)d_in[16];
    float* out = (float*)d_out;

    char* ws = (char*)d_ws;
    int* indeg   = (int*)ws;  ws += (size_t)N_NODES * sizeof(int);
    int* outdeg  = (int*)ws;  ws += (size_t)N_NODES * sizeof(int);
    int* rowptr  = (int*)ws;  ws += (size_t)(N_NODES + 4) * sizeof(int);
    int* partials= (int*)ws;  ws += 128 * sizeof(int);
    float* norm_src = (float*)ws; ws += (size_t)N_NODES * sizeof(float);
    float* norm_dst = (float*)ws; ws += (size_t)N_NODES * sizeof(float);
    bf16_t* Wt1 = (bf16_t*)ws; ws += (size_t)128 * IN_FEATS * sizeof(bf16_t);
    bf16_t* Wt2 = (bf16_t*)ws; ws += (size_t)128 * HIDDEN * sizeof(bf16_t);
    bf16_t* Wt3 = (bf16_t*)ws; ws += (size_t)128 * HIDDEN * sizeof(bf16_t);
    int* csr_src = (int*)ws;  ws += (size_t)N_EDGES * sizeof(int);
    bf16_t* bufB = (bf16_t*)ws; ws += (size_t)N_NODES * HIDDEN * sizeof(bf16_t);
    // union 1: h_dst (alive histo..sortT) / bufA (alive after sortT)
    unsigned char* h_dst = (unsigned char*)ws;
    bf16_t* bufA = (bf16_t*)ws;
    ws += (size_t)G_SORT * N_NODES;                                  // 25.6 MB
    // union 2: h_src (alive histo..colsum) / xb + emb + cnt
    unsigned char* h_src = (unsigned char*)ws;
    bf16_t* xb   = (bf16_t*)ws;
    float* emb   = (float*)(ws + (size_t)N_NODES * IN_FEATS * sizeof(bf16_t));
    float* cnt   = emb + (size_t)N_GRAPHS * HIDDEN;
    ws += (size_t)G_SORT * N_NODES;                                  // 25.6 MB

    // ---- CSR build (counting sort, no global atomics) ----
    histo_kernel<<<G_SORT, 512, 0, stream>>>(src, dst, h_src, h_dst);
    colsum_kernel<<<(N_NODES + 255) / 256, 256, 0, stream>>>(h_src, outdeg);
    scanp_kernel<<<(N_NODES + 255) / 256, 256, 0, stream>>>(h_dst, indeg);
    scanA<<<NB_CHUNKS, 256, 0, stream>>>(indeg, partials);
    scanB<<<1, 128, 0, stream>>>(partials, rowptr);
    scanC<<<NB_CHUNKS, 256, 0, stream>>>(indeg, partials, rowptr);
    norm_kernel<<<(N_NODES + 255) / 256, 256, 0, stream>>>(outdeg, indeg, norm_src, norm_dst);
    sortT_kernel<<<G_SORT, 512, 0, stream>>>(src, dst, h_dst, rowptr, csr_src);

    // ---- weight prep + prescale (xb overlays h_src: dead after colsum) ----
    wprep_kernel<<<(128 * IN_FEATS + 255) / 256, 256, 0, stream>>>(W1, Wt1, IN_FEATS);
    wprep_kernel<<<(128 * HIDDEN + 255) / 256, 256, 0, stream>>>(W2, Wt2, HIDDEN);
    wprep_kernel<<<(128 * HIDDEN + 255) / 256, 256, 0, stream>>>(W3, Wt3, HIDDEN);
    prescale_kernel<<<(N_NODES * (IN_FEATS / 4) + 255) / 256, 256, 0, stream>>>(feats_node, norm_src, xb);

    const int mm_grid = (N_NODES + 63) / 64;
    const int gp_grid = 8 * ((N_NODES + 7) / 8);   // 8 panels x 12500 node-octets

    // layer 1: matmul-first (xb row-major 64 -> panel-major 128), then panel gather
    node_matmul_mfma<IN_FEATS, false><<<mm_grid, 256, 0, stream>>>(xb, Wt1, bufB);
    gatherP_kernel<true><<<gp_grid, 256, 0, stream>>>(bufB, rowptr, csr_src, norm_dst, norm_src, b1, bufA);

    // layer 2
    node_matmul_mfma<HIDDEN, true><<<mm_grid, 256, 0, stream>>>(bufA, Wt2, bufB);
    gatherP_kernel<true><<<gp_grid, 256, 0, stream>>>(bufB, rowptr, csr_src, norm_dst, norm_src, b2, bufA);

    // layer 3 (no nsrc on output; feeds pooling)
    node_matmul_mfma<HIDDEN, true><<<mm_grid, 256, 0, stream>>>(bufA, Wt3, bufB);
    gatherP_kernel<false><<<gp_grid, 256, 0, stream>>>(bufB, rowptr, csr_src, norm_dst, norm_src, b3, bufA);

    // readout + MLP
    hipMemsetAsync(emb, 0, ((size_t)N_GRAPHS * HIDDEN + N_GRAPHS) * sizeof(float), stream);
    const int n_waves = (N_NODES + 63) / 64;
    pool_kernel<<<(n_waves + 3) / 4, 256, 0, stream>>>(bufA, gid, emb, cnt);
    mlp_kernel<<<N_GRAPHS, 256, 0, stream>>>(emb, cnt, feats_graph,
                                             M1, c1, M2, c2, M3, c3, out);
}

// Round 8
// 780.353 us; speedup vs baseline: 1.4509x; 1.1760x over previous
//
#include <hip/hip_runtime.h>
#include <hip/hip_bf16.h>
#include <cstddef>

#define N_NODES 100000
#define N_EDGES 3200000
#define N_GRAPHS 2048
#define IN_FEATS 64
#define HIDDEN 128
#define EXTRA 8

#define SCAN_CHUNK 1024
#define NB_CHUNKS ((N_NODES + SCAN_CHUNK - 1) / SCAN_CHUNK)  // 98

// counting-sort parameters
#define R_BINS 16000                 // sortT: 16000 u32 bins = 64000 B LDS
#define NPASS 7                      // 7 * 16000 >= 100000
#define R_BINS_H 32000               // histo: 32000 u16 bins packed in 16000 u32
#define NPASS_H 4                    // 4 * 32000 >= 100000
#define G_SORT 256
#define CHUNK (N_EDGES / G_SORT)     // 12500

typedef unsigned short bf16_t;
typedef short bfx8 __attribute__((ext_vector_type(8)));
typedef float f32x4 __attribute__((ext_vector_type(4)));

__device__ __forceinline__ float selu_f(float x) {
    const float scale = 1.0507009873554805f;
    const float alpha = 1.6732632423543772f;
    return x > 0.f ? scale * x : scale * alpha * (__expf(x) - 1.f);
}
__device__ __forceinline__ float bf2f(unsigned short u) {
    union { unsigned int i; float f; } c; c.i = ((unsigned int)u) << 16; return c.f;
}
__device__ __forceinline__ unsigned short f2bf(float f) {
    union { float f; unsigned int i; } c; c.f = f;
    unsigned int lsb = (c.i >> 16) & 1;
    c.i += 0x7fffu + lsb;                 // round to nearest even
    return (unsigned short)(c.i >> 16);
}

// ============ counting-sort CSR build (no global atomics) ============

// dual-u16 packed LDS histogram: 32000 bins/pass in 16000 u32 words
__global__ __launch_bounds__(512) void histo_kernel(const int* __restrict__ src,
                                                    const int* __restrict__ dst,
                                                    unsigned char* __restrict__ h_src,
                                                    unsigned char* __restrict__ h_dst) {
    __shared__ unsigned int hist[R_BINS_H / 2];
    const int b = blockIdx.x, t = threadIdx.x;
    const int e0 = b * CHUNK;
#pragma unroll
    for (int ph = 0; ph < 2; ++ph) {
        const int4* key4 = (const int4*)((ph ? src : dst) + e0);
        unsigned char* hout = (ph ? h_src : h_dst) + (size_t)b * N_NODES;
        for (int p = 0; p < NPASS_H; ++p) {
            const int r0 = p * R_BINS_H;
            const int rend = min(R_BINS_H, N_NODES - r0);
            for (int i = t; i < R_BINS_H / 2; i += 512) hist[i] = 0;
            __syncthreads();
            for (int i = t; i < CHUNK / 4; i += 512) {
                int4 k = key4[i];
                unsigned int x;
                x = (unsigned)(k.x - r0); if (x < (unsigned)R_BINS_H) atomicAdd(&hist[x >> 1], 1u << ((x & 1) << 4));
                x = (unsigned)(k.y - r0); if (x < (unsigned)R_BINS_H) atomicAdd(&hist[x >> 1], 1u << ((x & 1) << 4));
                x = (unsigned)(k.z - r0); if (x < (unsigned)R_BINS_H) atomicAdd(&hist[x >> 1], 1u << ((x & 1) << 4));
                x = (unsigned)(k.w - r0); if (x < (unsigned)R_BINS_H) atomicAdd(&hist[x >> 1], 1u << ((x & 1) << 4));
            }
            __syncthreads();
            for (int i = t; i < rend; i += 512)
                hout[r0 + i] = (unsigned char)((hist[i >> 1] >> ((i & 1) << 4)) & 0xffffu);
            __syncthreads();
        }
    }
}

__global__ __launch_bounds__(256) void colsum_kernel(const unsigned char* __restrict__ h_src,
                                                     int* __restrict__ outdeg) {
    int bin = blockIdx.x * 256 + threadIdx.x;
    if (bin >= N_NODES) return;
    int s = 0;
#pragma unroll 8
    for (int b = 0; b < G_SORT; ++b) s += h_src[(size_t)b * N_NODES + bin];
    outdeg[bin] = s;
}

__global__ __launch_bounds__(256) void scanp_kernel(unsigned char* __restrict__ h_dst,
                                                    int* __restrict__ indeg) {
    int bin = blockIdx.x * 256 + threadIdx.x;
    if (bin >= N_NODES) return;
    int run = 0;
#pragma unroll 8
    for (int b = 0; b < G_SORT; ++b) {
        size_t off = (size_t)b * N_NODES + bin;
        int v = h_dst[off];
        h_dst[off] = (unsigned char)run;
        run += v;
    }
    indeg[bin] = run;
}

__global__ __launch_bounds__(512) void sortT_kernel(const int* __restrict__ src,
                                                    const int* __restrict__ dst,
                                                    const unsigned char* __restrict__ h_dst,
                                                    const int* __restrict__ rowptr,
                                                    int* __restrict__ csr_src) {
    __shared__ unsigned int cnt[R_BINS];
    const int b = blockIdx.x, t = threadIdx.x;
    const int e0 = b * CHUNK;
    const int4* d4p = (const int4*)(dst + e0);
    const int4* s4p = (const int4*)(src + e0);
    const unsigned char* hrow = h_dst + (size_t)b * N_NODES;
    for (int p = 0; p < NPASS; ++p) {
        const int r0 = p * R_BINS;
        const unsigned int rend = (unsigned)min(R_BINS, N_NODES - r0);
        for (int i = t; i < (int)rend; i += 512)
            cnt[i] = (unsigned)rowptr[r0 + i] + (unsigned)hrow[r0 + i];
        __syncthreads();
        for (int i = t; i < CHUNK / 4; i += 512) {
            int4 d = d4p[i];
            int4 s = s4p[i];
            unsigned int x;
            x = (unsigned)(d.x - r0); if (x < rend) { unsigned slot = atomicAdd(&cnt[x], 1u); csr_src[slot] = s.x; }
            x = (unsigned)(d.y - r0); if (x < rend) { unsigned slot = atomicAdd(&cnt[x], 1u); csr_src[slot] = s.y; }
            x = (unsigned)(d.z - r0); if (x < rend) { unsigned slot = atomicAdd(&cnt[x], 1u); csr_src[slot] = s.z; }
            x = (unsigned)(d.w - r0); if (x < rend) { unsigned slot = atomicAdd(&cnt[x], 1u); csr_src[slot] = s.w; }
        }
        __syncthreads();
    }
}

// ============ norms, rowptr scan, weights, features ============

__global__ __launch_bounds__(256) void norm_kernel(const int* __restrict__ outdeg,
                                                   const int* __restrict__ indeg,
                                                   float* __restrict__ nsrc,
                                                   float* __restrict__ ndst) {
    int i = blockIdx.x * 256 + threadIdx.x;
    if (i < N_NODES) {
        nsrc[i] = rsqrtf(fmaxf((float)outdeg[i], 1.f));
        ndst[i] = rsqrtf(fmaxf((float)indeg[i], 1.f));
    }
}

__global__ __launch_bounds__(256) void scanA(const int* __restrict__ indeg,
                                             int* __restrict__ partials) {
    __shared__ int red[4];
    const int b = blockIdx.x, t = threadIdx.x;
    int base = b * SCAN_CHUNK + t * 4;
    int s = 0;
#pragma unroll
    for (int k = 0; k < 4; ++k) { int i = base + k; if (i < N_NODES) s += indeg[i]; }
    for (int off = 32; off; off >>= 1) s += __shfl_down(s, off);
    if ((t & 63) == 0) red[t >> 6] = s;
    __syncthreads();
    if (t == 0) partials[b] = red[0] + red[1] + red[2] + red[3];
}

__global__ __launch_bounds__(128) void scanB(int* __restrict__ partials,
                                             int* __restrict__ rowptr) {
    __shared__ int s[128];
    const int t = threadIdx.x;
    int v = (t < NB_CHUNKS) ? partials[t] : 0;
    s[t] = v;
    __syncthreads();
    for (int off = 1; off < 128; off <<= 1) {
        int u = (t >= off) ? s[t - off] : 0;
        __syncthreads();
        s[t] += u;
        __syncthreads();
    }
    if (t < NB_CHUNKS) partials[t] = s[t] - v;   // exclusive
    if (t == 127) rowptr[N_NODES] = s[127];
}

__global__ __launch_bounds__(256) void scanC(const int* __restrict__ indeg,
                                             const int* __restrict__ partials,
                                             int* __restrict__ rowptr) {
    __shared__ int ts[256];
    const int b = blockIdx.x, t = threadIdx.x;
    int base = b * SCAN_CHUNK + t * 4;
    int v[4];
    int s = 0;
#pragma unroll
    for (int k = 0; k < 4; ++k) { int i = base + k; v[k] = (i < N_NODES) ? indeg[i] : 0; s += v[k]; }
    ts[t] = s;
    __syncthreads();
    for (int off = 1; off < 256; off <<= 1) {
        int u = (t >= off) ? ts[t - off] : 0;
        __syncthreads();
        ts[t] += u;
        __syncthreads();
    }
    int excl = ts[t] - s + partials[b];
#pragma unroll
    for (int k = 0; k < 4; ++k) {
        int i = base + k;
        if (i < N_NODES) rowptr[i] = excl;
        excl += v[k];
    }
}

__global__ __launch_bounds__(256) void wprep_kernel(const float* __restrict__ W,
                                                    bf16_t* __restrict__ Wt, int K) {
    int i = blockIdx.x * 256 + threadIdx.x;
    if (i >= 128 * K) return;
    int n = i / K, k = i - n * K;
    Wt[i] = f2bf(W[k * 128 + n]);
}

// prescale: xb4 = bf16(x * nsrc), panel-major [4][N][16]
__global__ __launch_bounds__(256) void prescale_kernel(const float* __restrict__ x,
                                                       const float* __restrict__ nsrc,
                                                       bf16_t* __restrict__ xb4) {
    int i = blockIdx.x * 256 + threadIdx.x;
    const int total = N_NODES * (IN_FEATS / 4);
    if (i >= total) return;
    int node = i >> 4;
    int c4 = i & 15;
    float nm = nsrc[node];
    float4 v = ((const float4*)x)[i];
    ushort4 o;
    o.x = f2bf(v.x * nm); o.y = f2bf(v.y * nm);
    o.z = f2bf(v.z * nm); o.w = f2bf(v.w * nm);
    *(ushort4*)(xb4 + (((size_t)(c4 >> 2) * N_NODES + node) * 16) + (c4 & 3) * 4) = o;
}

// ============ panel gather v3: batch-hoisted predicated loads ============
// Layout [NP][N][16] bf16, NP = 1<<LOGP panels; blockIdx & (NP-1) = panel
// (XCD-pinned by round-robin dispatch; 3.2 MB panel L2-resident — verified
// r6/r7: FETCH 512->68 MB). Wave = 2 nodes x 8 edge-slots x 4 feat-quads.
// Indices for indeg<=64 are loaded in two predicated batches (clamped dup
// loads coalesce), breaking the csr->feature dependent-latency chain.
template <int LOGP, bool EPI, bool SCALE_OUT>
__global__ __launch_bounds__(256) void gatherP_kernel(const bf16_t* __restrict__ hP,
                                                      const int* __restrict__ rowptr,
                                                      const int* __restrict__ csr_src,
                                                      const float* __restrict__ ndst,
                                                      const float* __restrict__ nsrc,
                                                      const float* __restrict__ bias,
                                                      bf16_t* __restrict__ outP) {
    const int p = blockIdx.x & ((1 << LOGP) - 1);
    const int l = threadIdx.x & 63;
    const int node = ((blockIdx.x >> LOGP) << 3) + ((threadIdx.x >> 6) << 1) + (l >> 5);
    const int es = (l >> 2) & 7;          // edge slot 0..7
    const int q  = l & 3;                 // feat quad 0..3
    const char* bp = (const char*)(hP + (size_t)p * (N_NODES * 16) + q * 4);

    const int r0 = rowptr[node], r1 = rowptr[node + 1];
    float a0 = 0.f, a1 = 0.f, a2 = 0.f, a3 = 0.f;
    if (r1 > r0) {
        const int cl = r1 - 1;
        const int e = r0 + es;
        {   // batch 1: edges r0 .. r0+31
            int p0 = min(e, cl),      p1 = min(e + 8, cl);
            int p2 = min(e + 16, cl), p3 = min(e + 24, cl);
            int s0 = csr_src[p0], s1 = csr_src[p1], s2 = csr_src[p2], s3 = csr_src[p3];
            ushort4 u0 = *(const ushort4*)(bp + ((unsigned)s0 << 5));
            ushort4 u1 = *(const ushort4*)(bp + ((unsigned)s1 << 5));
            ushort4 u2 = *(const ushort4*)(bp + ((unsigned)s2 << 5));
            ushort4 u3 = *(const ushort4*)(bp + ((unsigned)s3 << 5));
            if (e < r1)      { a0 += bf2f(u0.x); a1 += bf2f(u0.y); a2 += bf2f(u0.z); a3 += bf2f(u0.w); }
            if (e + 8 < r1)  { a0 += bf2f(u1.x); a1 += bf2f(u1.y); a2 += bf2f(u1.z); a3 += bf2f(u1.w); }
            if (e + 16 < r1) { a0 += bf2f(u2.x); a1 += bf2f(u2.y); a2 += bf2f(u2.z); a3 += bf2f(u2.w); }
            if (e + 24 < r1) { a0 += bf2f(u3.x); a1 += bf2f(u3.y); a2 += bf2f(u3.z); a3 += bf2f(u3.w); }
        }
        if (r1 > r0 + 32) {  // batch 2: edges r0+32 .. r0+63
            int e2 = e + 32;
            int p0 = min(e2, cl),      p1 = min(e2 + 8, cl);
            int p2 = min(e2 + 16, cl), p3 = min(e2 + 24, cl);
            int s0 = csr_src[p0], s1 = csr_src[p1], s2 = csr_src[p2], s3 = csr_src[p3];
            ushort4 u0 = *(const ushort4*)(bp + ((unsigned)s0 << 5));
            ushort4 u1 = *(const ushort4*)(bp + ((unsigned)s1 << 5));
            ushort4 u2 = *(const ushort4*)(bp + ((unsigned)s2 << 5));
            ushort4 u3 = *(const ushort4*)(bp + ((unsigned)s3 << 5));
            if (e2 < r1)      { a0 += bf2f(u0.x); a1 += bf2f(u0.y); a2 += bf2f(u0.z); a3 += bf2f(u0.w); }
            if (e2 + 8 < r1)  { a0 += bf2f(u1.x); a1 += bf2f(u1.y); a2 += bf2f(u1.z); a3 += bf2f(u1.w); }
            if (e2 + 16 < r1) { a0 += bf2f(u2.x); a1 += bf2f(u2.y); a2 += bf2f(u2.z); a3 += bf2f(u2.w); }
            if (e2 + 24 < r1) { a0 += bf2f(u3.x); a1 += bf2f(u3.y); a2 += bf2f(u3.z); a3 += bf2f(u3.w); }
            // rare tail: indeg > 64
            for (int ee = r0 + 64 + es; ee < r1; ee += 8) {
                int s = csr_src[ee];
                ushort4 u = *(const ushort4*)(bp + ((unsigned)s << 5));
                a0 += bf2f(u.x); a1 += bf2f(u.y); a2 += bf2f(u.z); a3 += bf2f(u.w);
            }
        }
    }
#pragma unroll
    for (int m = 4; m <= 16; m <<= 1) {
        a0 += __shfl_xor(a0, m); a1 += __shfl_xor(a1, m);
        a2 += __shfl_xor(a2, m); a3 += __shfl_xor(a3, m);
    }
    if (es == 0) {
        const float nm = ndst[node];
        float v0, v1, v2, v3;
        if (EPI) {
            const int f0 = p * 16 + q * 4;
            v0 = selu_f(a0 * nm + bias[f0]);
            v1 = selu_f(a1 * nm + bias[f0 + 1]);
            v2 = selu_f(a2 * nm + bias[f0 + 2]);
            v3 = selu_f(a3 * nm + bias[f0 + 3]);
            if (SCALE_OUT) { float sc = nsrc[node]; v0 *= sc; v1 *= sc; v2 *= sc; v3 *= sc; }
        } else {
            v0 = a0 * nm; v1 = a1 * nm; v2 = a2 * nm; v3 = a3 * nm;
        }
        ushort4 o; o.x = f2bf(v0); o.y = f2bf(v1); o.z = f2bf(v2); o.w = f2bf(v3);
        *(ushort4*)(outP + ((size_t)p * N_NODES + node) * 16 + q * 4) = o;
    }
}

// ============ MFMA node matmul: panel-major in/out ============
// A_PANEL: input [K/16][N][16]; else row-major [N][K]. EPI: bias+selu(+nsrc).
template <int K, bool A_PANEL, bool EPI, bool SCALE_OUT>
__global__ __launch_bounds__(256) void node_matmul_mfma(const bf16_t* __restrict__ Hb,
                                                        const bf16_t* __restrict__ Wt,
                                                        const float* __restrict__ bias,
                                                        const float* __restrict__ nsrc,
                                                        bf16_t* __restrict__ outP) {
    __shared__ char sW[128 * K * 2];
    const int t = threadIdx.x;

    for (int fb = t * 16; fb < 128 * K * 2; fb += 256 * 16) {
        bfx8 v = *(const bfx8*)((const char*)Wt + fb);
        int n = fb / (2 * K);
        *(bfx8*)(sW + (fb ^ ((n & 7) << 4))) = v;
    }
    __syncthreads();

    const int wv = t >> 6;
    const int l  = t & 63;
    const int m  = l & 15;
    const int kb = l >> 4;
    const int row0 = blockIdx.x * 64 + wv * 16;

    int arow = row0 + m;
    if (arow > N_NODES - 1) arow = N_NODES - 1;

    f32x4 acc[8];
#pragma unroll
    for (int f = 0; f < 8; ++f) acc[f] = (f32x4){0.f, 0.f, 0.f, 0.f};

#pragma unroll
    for (int kc = 0; kc < K / 32; ++kc) {
        const char* ap;
        if (A_PANEL) {
            int fb = kc * 64 + kb * 16;          // byte offset within feature row
            int pp = fb >> 5;
            ap = (const char*)Hb + ((size_t)pp * N_NODES + arow) * 32 + (fb & 31);
        } else {
            ap = (const char*)(Hb + (size_t)arow * K) + kc * 64 + kb * 16;
        }
        bfx8 a = *(const bfx8*)ap;
#pragma unroll
        for (int f = 0; f < 8; ++f) {
            int n = f * 16 + m;
            int off = n * (2 * K) + kc * 64 + kb * 16;
            off ^= (n & 7) << 4;
            bfx8 b = *(const bfx8*)(sW + off);
            acc[f] = __builtin_amdgcn_mfma_f32_16x16x32_bf16(a, b, acc[f], 0, 0, 0);
        }
    }

    // D[m'][n]: node m' = row0 + kb*4 + j ; feat n = f*16 + m -> panel f, elem m
    float nm[4];
#pragma unroll
    for (int j = 0; j < 4; ++j) {
        nm[j] = 1.f;
        if (EPI && SCALE_OUT) {
            int node = row0 + kb * 4 + j;
            if (node < N_NODES) nm[j] = nsrc[node];
        }
    }
#pragma unroll
    for (int f = 0; f < 8; ++f) {
        int feat = f * 16 + m;
        float bb = EPI ? bias[feat] : 0.f;
        bf16_t* op = outP + (size_t)f * N_NODES * 16 + m;
#pragma unroll
        for (int j = 0; j < 4; ++j) {
            int node = row0 + kb * 4 + j;
            if (node < N_NODES) {
                float v = EPI ? (selu_f(acc[f][j] + bb) * nm[j]) : acc[f][j];
                op[(size_t)node * 16] = f2bf(v);
            }
        }
    }
}

// ============ pool (panel-major input) + MLP head ============
__global__ __launch_bounds__(256) void pool_kernel(const bf16_t* __restrict__ hP,
                                                   const int* __restrict__ gid,
                                                   float* __restrict__ emb,
                                                   float* __restrict__ cnt) {
    const int lane = threadIdx.x & 63;
    const int wid = (blockIdx.x * 256 + threadIdx.x) >> 6;
    const int n0 = wid * 64;
    if (n0 >= N_NODES) return;
    const int nend = (n0 + 64 < N_NODES) ? n0 + 64 : N_NODES;
    const bf16_t* bp = hP + (size_t)(lane >> 3) * N_NODES * 16 + (lane & 7) * 2;
    int cur = gid[n0];
    float ax = 0.f, ay = 0.f, run = 0.f;
    for (int n = n0; n < nend; ++n) {
        int g = gid[n];
        if (g != cur) {
            atomicAdd(&emb[(size_t)cur * HIDDEN + lane * 2], ax);
            atomicAdd(&emb[(size_t)cur * HIDDEN + lane * 2 + 1], ay);
            if (lane == 0) atomicAdd(&cnt[cur], run);
            cur = g; ax = 0.f; ay = 0.f; run = 0.f;
        }
        ushort2 u = *(const ushort2*)(bp + (size_t)n * 16);
        ax += bf2f(u.x); ay += bf2f(u.y);
        run += 1.f;
    }
    atomicAdd(&emb[(size_t)cur * HIDDEN + lane * 2], ax);
    atomicAdd(&emb[(size_t)cur * HIDDEN + lane * 2 + 1], ay);
    if (lane == 0) atomicAdd(&cnt[cur], run);
}

__global__ __launch_bounds__(256) void mlp_kernel(const float* __restrict__ emb,
                                                  const float* __restrict__ cnt,
                                                  const float* __restrict__ fg,
                                                  const float* __restrict__ M1, const float* __restrict__ c1,
                                                  const float* __restrict__ M2, const float* __restrict__ c2,
                                                  const float* __restrict__ M3, const float* __restrict__ c3,
                                                  float* __restrict__ out) {
    const int g = blockIdx.x;
    const int t = threadIdx.x;
    __shared__ float z[HIDDEN + EXTRA];
    __shared__ float z1[2 * HIDDEN];
    __shared__ float z2[HIDDEN];
    if (t < HIDDEN) {
        float c = fmaxf(cnt[g], 1.f);
        z[t] = emb[(size_t)g * HIDDEN + t] / c;
    } else if (t < HIDDEN + EXTRA) {
        z[t] = fg[g * EXTRA + (t - HIDDEN)];
    }
    __syncthreads();
    {
        float s = c1[t];
        for (int k = 0; k < HIDDEN + EXTRA; ++k) s += z[k] * M1[k * (2 * HIDDEN) + t];
        z1[t] = selu_f(s);
    }
    __syncthreads();
    if (t < HIDDEN) {
        float s = c2[t];
        for (int k = 0; k < 2 * HIDDEN; ++k) s += z1[k] * M2[k * HIDDEN + t];
        z2[t] = selu_f(s);
    }
    __syncthreads();
    if (t < 64) {
        float s = z2[t] * M3[t] + z2[t + 64] * M3[t + 64];
#pragma unroll
        for (int off = 32; off; off >>= 1) s += __shfl_down(s, off);
        if (t == 0) out[g] = s + c3[0];
    }
}

extern "C" void kernel_launch(void* const* d_in, const int* in_sizes, int n_in,
                              void* d_out, int out_size, void* d_ws, size_t ws_size,
                              hipStream_t stream) {
    const float* feats_node  = (const float*)d_in[0];
    const float* feats_graph = (const float*)d_in[1];
    const int*   src         = (const int*)d_in[2];
    const int*   dst         = (const int*)d_in[3];
    const int*   gid         = (const int*)d_in[4];
    const float* W1 = (const float*)d_in[5];
    const float* b1 = (const float*)d_in[6];
    const float* W2 = (const float*)d_in[7];
    const float* b2 = (const float*)d_in[8];
    const float* W3 = (const float*)d_in[9];
    const float* b3 = (const float*)d_in[10];
    const float* M1 = (const float*)d_in[11];
    const float* c1 = (const float*)d_in[12];
    const float* M2 = (const float*)d_in[13];
    const float* c2 = (const float*)d_in[14];
    const float* M3 = (const float*)d_in[15];
    const float* c3 = (const float*)d_in[16];
    float* out = (float*)d_out;

    char* ws = (char*)d_ws;
    int* indeg   = (int*)ws;  ws += (size_t)N_NODES * sizeof(int);
    int* outdeg  = (int*)ws;  ws += (size_t)N_NODES * sizeof(int);
    int* rowptr  = (int*)ws;  ws += (size_t)(N_NODES + 4) * sizeof(int);
    int* partials= (int*)ws;  ws += 128 * sizeof(int);
    float* norm_src = (float*)ws; ws += (size_t)N_NODES * sizeof(float);
    float* norm_dst = (float*)ws; ws += (size_t)N_NODES * sizeof(float);
    bf16_t* Wt1 = (bf16_t*)ws; ws += (size_t)128 * IN_FEATS * sizeof(bf16_t);
    bf16_t* Wt2 = (bf16_t*)ws; ws += (size_t)128 * HIDDEN * sizeof(bf16_t);
    bf16_t* Wt3 = (bf16_t*)ws; ws += (size_t)128 * HIDDEN * sizeof(bf16_t);
    int* csr_src = (int*)ws;  ws += (size_t)N_EDGES * sizeof(int);
    bf16_t* bufB = (bf16_t*)ws; ws += (size_t)N_NODES * HIDDEN * sizeof(bf16_t);
    // union 1: h_dst (alive histo..sortT) / bufA (m2, m3) / emb+cnt (after gather3)
    unsigned char* h_dst = (unsigned char*)ws;
    bf16_t* bufA = (bf16_t*)ws;
    float* emb   = (float*)ws;
    float* cnt   = emb + (size_t)N_GRAPHS * HIDDEN;
    ws += (size_t)G_SORT * N_NODES;                                  // 25.6 MB
    // union 2: h_src (alive histo..colsum) / xb4 + g4 (panel-major 64f)
    unsigned char* h_src = (unsigned char*)ws;
    bf16_t* xb4  = (bf16_t*)ws;
    bf16_t* g4   = xb4 + (size_t)N_NODES * IN_FEATS;
    ws += (size_t)G_SORT * N_NODES;                                  // 25.6 MB

    // ---- CSR build (counting sort, no global atomics) ----
    histo_kernel<<<G_SORT, 512, 0, stream>>>(src, dst, h_src, h_dst);
    colsum_kernel<<<(N_NODES + 255) / 256, 256, 0, stream>>>(h_src, outdeg);
    scanp_kernel<<<(N_NODES + 255) / 256, 256, 0, stream>>>(h_dst, indeg);
    scanA<<<NB_CHUNKS, 256, 0, stream>>>(indeg, partials);
    scanB<<<1, 128, 0, stream>>>(partials, rowptr);
    scanC<<<NB_CHUNKS, 256, 0, stream>>>(indeg, partials, rowptr);
    norm_kernel<<<(N_NODES + 255) / 256, 256, 0, stream>>>(outdeg, indeg, norm_src, norm_dst);
    sortT_kernel<<<G_SORT, 512, 0, stream>>>(src, dst, h_dst, rowptr, csr_src);

    // ---- weight prep + prescale (xb4 overlays h_src: dead after colsum) ----
    wprep_kernel<<<(128 * IN_FEATS + 255) / 256, 256, 0, stream>>>(W1, Wt1, IN_FEATS);
    wprep_kernel<<<(128 * HIDDEN + 255) / 256, 256, 0, stream>>>(W2, Wt2, HIDDEN);
    wprep_kernel<<<(128 * HIDDEN + 255) / 256, 256, 0, stream>>>(W3, Wt3, HIDDEN);
    prescale_kernel<<<(N_NODES * (IN_FEATS / 4) + 255) / 256, 256, 0, stream>>>(feats_node, norm_src, xb4);

    const int mm_grid = (N_NODES + 63) / 64;
    const int gp4_grid = 4 * (N_NODES / 8);    // 4 panels x 12500 node-octets
    const int gp8_grid = 8 * (N_NODES / 8);    // 8 panels x 12500

    // layer 1: gather-first on 64 feats, then MFMA matmul w/ epilogue
    gatherP_kernel<2, false, false><<<gp4_grid, 256, 0, stream>>>(xb4, rowptr, csr_src, norm_dst, norm_src, b1, g4);
    node_matmul_mfma<IN_FEATS, true, true, true><<<mm_grid, 256, 0, stream>>>(g4, Wt1, b1, norm_src, bufB);

    // layer 2: raw matmul, gather applies epilogue
    node_matmul_mfma<HIDDEN, true, false, false><<<mm_grid, 256, 0, stream>>>(bufB, Wt2, b2, norm_src, bufA);
    gatherP_kernel<3, true, true><<<gp8_grid, 256, 0, stream>>>(bufA, rowptr, csr_src, norm_dst, norm_src, b2, bufB);

    // layer 3 (no nsrc on output; feeds pooling)
    node_matmul_mfma<HIDDEN, true, false, false><<<mm_grid, 256, 0, stream>>>(bufB, Wt3, b3, norm_src, bufA);
    gatherP_kernel<3, true, false><<<gp8_grid, 256, 0, stream>>>(bufA, rowptr, csr_src, norm_dst, norm_src, b3, bufB);

    // readout + MLP (emb overlays bufA: m3 dead after gather3)
    hipMemsetAsync(emb, 0, ((size_t)N_GRAPHS * HIDDEN + N_GRAPHS) * sizeof(float), stream);
    const int n_waves = (N_NODES + 63) / 64;
    pool_kernel<<<(n_waves + 3) / 4, 256, 0, stream>>>(bufB, gid, emb, cnt);
    mlp_kernel<<<N_GRAPHS, 256, 0, stream>>>(emb, cnt, feats_graph,
                                             M1, c1, M2, c2, M3, c3, out);
}

// Round 9
// 681.169 us; speedup vs baseline: 1.6622x; 1.1456x over previous
//
#include <hip/hip_runtime.h>
#include <hip/hip_bf16.h>
#include <cstddef>

#define N_NODES 100000
#define N_EDGES 3200000
#define N_GRAPHS 2048
#define IN_FEATS 64
#define HIDDEN 128
#define EXTRA 8

#define SCAN_CHUNK 1024
#define NB_CHUNKS ((N_NODES + SCAN_CHUNK - 1) / SCAN_CHUNK)  // 98

// counting-sort parameters
#define R_BINS 16000                 // sortT: u32 bins, 64000 B LDS
#define NPASS 7                      // 7 * 16000 >= 100000
#define R_BINS_H 32000               // histo: u16-packed bins in 16000 u32
#define NPASS_H 4                    // 4 * 32000 >= 100000
#define G_SORT 256
#define CHUNK (N_EDGES / G_SORT)     // 12500

typedef unsigned short bf16_t;
typedef short bfx8 __attribute__((ext_vector_type(8)));
typedef float f32x4 __attribute__((ext_vector_type(4)));

__device__ __forceinline__ float selu_f(float x) {
    const float scale = 1.0507009873554805f;
    const float alpha = 1.6732632423543772f;
    return x > 0.f ? scale * x : scale * alpha * (__expf(x) - 1.f);
}
__device__ __forceinline__ float bf2f(unsigned short u) {
    union { unsigned int i; float f; } c; c.i = ((unsigned int)u) << 16; return c.f;
}
__device__ __forceinline__ unsigned short f2bf(float f) {
    union { float f; unsigned int i; } c; c.f = f;
    unsigned int lsb = (c.i >> 16) & 1;
    c.i += 0x7fffu + lsb;                 // round to nearest even
    return (unsigned short)(c.i >> 16);
}

// ============ counting-sort CSR build (no global atomics) ============

// dual-u16 packed LDS histogram: 32000 bins/pass in 16000 u32 words
__global__ __launch_bounds__(512) void histo_kernel(const int* __restrict__ src,
                                                    const int* __restrict__ dst,
                                                    unsigned char* __restrict__ h_src,
                                                    unsigned char* __restrict__ h_dst) {
    __shared__ unsigned int hist[R_BINS_H / 2];
    const int b = blockIdx.x, t = threadIdx.x;
    const int e0 = b * CHUNK;
#pragma unroll
    for (int ph = 0; ph < 2; ++ph) {
        const int4* key4 = (const int4*)((ph ? src : dst) + e0);
        unsigned char* hout = (ph ? h_src : h_dst) + (size_t)b * N_NODES;
        for (int p = 0; p < NPASS_H; ++p) {
            const int r0 = p * R_BINS_H;
            const int rend = min(R_BINS_H, N_NODES - r0);
            for (int i = t; i < R_BINS_H / 2; i += 512) hist[i] = 0;
            __syncthreads();
            for (int i = t; i < CHUNK / 4; i += 512) {
                int4 k = key4[i];
                unsigned int x;
                x = (unsigned)(k.x - r0); if (x < (unsigned)R_BINS_H) atomicAdd(&hist[x >> 1], 1u << ((x & 1) << 4));
                x = (unsigned)(k.y - r0); if (x < (unsigned)R_BINS_H) atomicAdd(&hist[x >> 1], 1u << ((x & 1) << 4));
                x = (unsigned)(k.z - r0); if (x < (unsigned)R_BINS_H) atomicAdd(&hist[x >> 1], 1u << ((x & 1) << 4));
                x = (unsigned)(k.w - r0); if (x < (unsigned)R_BINS_H) atomicAdd(&hist[x >> 1], 1u << ((x & 1) << 4));
            }
            __syncthreads();
            for (int i = t; i < rend; i += 512)
                hout[r0 + i] = (unsigned char)((hist[i >> 1] >> ((i & 1) << 4)) & 0xffffu);
            __syncthreads();
        }
    }
}

// merged: outdeg = colsum(h_src); h_dst -> in-place per-bin block prefix; indeg = total
__global__ __launch_bounds__(256) void degs_kernel(const unsigned char* __restrict__ h_src,
                                                   unsigned char* __restrict__ h_dst,
                                                   int* __restrict__ outdeg,
                                                   int* __restrict__ indeg) {
    int bin = blockIdx.x * 256 + threadIdx.x;
    if (bin >= N_NODES) return;
    int s = 0;
#pragma unroll 8
    for (int b = 0; b < G_SORT; ++b) s += h_src[(size_t)b * N_NODES + bin];
    outdeg[bin] = s;
    int run = 0;
#pragma unroll 8
    for (int b = 0; b < G_SORT; ++b) {
        size_t off = (size_t)b * N_NODES + bin;
        int v = h_dst[off];
        h_dst[off] = (unsigned char)run;
        run += v;
    }
    indeg[bin] = run;
}

__global__ __launch_bounds__(512) void sortT_kernel(const int* __restrict__ src,
                                                    const int* __restrict__ dst,
                                                    const unsigned char* __restrict__ h_dst,
                                                    const int* __restrict__ rowptr,
                                                    int* __restrict__ csr_src) {
    __shared__ unsigned int cnt[R_BINS];
    const int b = blockIdx.x, t = threadIdx.x;
    const int e0 = b * CHUNK;
    const int4* d4p = (const int4*)(dst + e0);
    const int4* s4p = (const int4*)(src + e0);
    const unsigned char* hrow = h_dst + (size_t)b * N_NODES;
    for (int p = 0; p < NPASS; ++p) {
        const int r0 = p * R_BINS;
        const unsigned int rend = (unsigned)min(R_BINS, N_NODES - r0);
        for (int i = t; i < (int)rend; i += 512)
            cnt[i] = (unsigned)rowptr[r0 + i] + (unsigned)hrow[r0 + i];
        __syncthreads();
        for (int i = t; i < CHUNK / 4; i += 512) {
            int4 d = d4p[i];
            int4 s = s4p[i];
            unsigned int x;
            x = (unsigned)(d.x - r0); if (x < rend) { unsigned slot = atomicAdd(&cnt[x], 1u); csr_src[slot] = s.x; }
            x = (unsigned)(d.y - r0); if (x < rend) { unsigned slot = atomicAdd(&cnt[x], 1u); csr_src[slot] = s.y; }
            x = (unsigned)(d.z - r0); if (x < rend) { unsigned slot = atomicAdd(&cnt[x], 1u); csr_src[slot] = s.z; }
            x = (unsigned)(d.w - r0); if (x < rend) { unsigned slot = atomicAdd(&cnt[x], 1u); csr_src[slot] = s.w; }
        }
        __syncthreads();
    }
}

// ============ norms, rowptr scan, weights, features ============

__global__ __launch_bounds__(256) void norm_kernel(const int* __restrict__ outdeg,
                                                   const int* __restrict__ indeg,
                                                   float* __restrict__ nsrc,
                                                   float* __restrict__ ndst) {
    int i = blockIdx.x * 256 + threadIdx.x;
    if (i < N_NODES) {
        nsrc[i] = rsqrtf(fmaxf((float)outdeg[i], 1.f));
        ndst[i] = rsqrtf(fmaxf((float)indeg[i], 1.f));
    }
}

__global__ __launch_bounds__(256) void scanA(const int* __restrict__ indeg,
                                             int* __restrict__ partials) {
    __shared__ int red[4];
    const int b = blockIdx.x, t = threadIdx.x;
    int base = b * SCAN_CHUNK + t * 4;
    int s = 0;
#pragma unroll
    for (int k = 0; k < 4; ++k) { int i = base + k; if (i < N_NODES) s += indeg[i]; }
    for (int off = 32; off; off >>= 1) s += __shfl_down(s, off);
    if ((t & 63) == 0) red[t >> 6] = s;
    __syncthreads();
    if (t == 0) partials[b] = red[0] + red[1] + red[2] + red[3];
}

__global__ __launch_bounds__(128) void scanB(int* __restrict__ partials,
                                             int* __restrict__ rowptr) {
    __shared__ int s[128];
    const int t = threadIdx.x;
    int v = (t < NB_CHUNKS) ? partials[t] : 0;
    s[t] = v;
    __syncthreads();
    for (int off = 1; off < 128; off <<= 1) {
        int u = (t >= off) ? s[t - off] : 0;
        __syncthreads();
        s[t] += u;
        __syncthreads();
    }
    if (t < NB_CHUNKS) partials[t] = s[t] - v;   // exclusive
    if (t == 127) rowptr[N_NODES] = s[127];
}

__global__ __launch_bounds__(256) void scanC(const int* __restrict__ indeg,
                                             const int* __restrict__ partials,
                                             int* __restrict__ rowptr) {
    __shared__ int ts[256];
    const int b = blockIdx.x, t = threadIdx.x;
    int base = b * SCAN_CHUNK + t * 4;
    int v[4];
    int s = 0;
#pragma unroll
    for (int k = 0; k < 4; ++k) { int i = base + k; v[k] = (i < N_NODES) ? indeg[i] : 0; s += v[k]; }
    ts[t] = s;
    __syncthreads();
    for (int off = 1; off < 256; off <<= 1) {
        int u = (t >= off) ? ts[t - off] : 0;
        __syncthreads();
        ts[t] += u;
        __syncthreads();
    }
    int excl = ts[t] - s + partials[b];
#pragma unroll
    for (int k = 0; k < 4; ++k) {
        int i = base + k;
        if (i < N_NODES) rowptr[i] = excl;
        excl += v[k];
    }
}

__global__ __launch_bounds__(256) void wprep_kernel(const float* __restrict__ W,
                                                    bf16_t* __restrict__ Wt, int K) {
    int i = blockIdx.x * 256 + threadIdx.x;
    if (i >= 128 * K) return;
    int n = i / K, k = i - n * K;
    Wt[i] = f2bf(W[k * 128 + n]);
}

__global__ __launch_bounds__(256) void prescale_kernel(const float* __restrict__ x,
                                                       const float* __restrict__ nsrc,
                                                       bf16_t* __restrict__ xb) {
    int i = blockIdx.x * 256 + threadIdx.x;
    const int total = N_NODES * (IN_FEATS / 4);
    if (i >= total) return;
    int node = i >> 4;                       // IN_FEATS/4 == 16
    float nm = nsrc[node];
    float4 v = ((const float4*)x)[i];
    ushort4 o;
    o.x = f2bf(v.x * nm); o.y = f2bf(v.y * nm);
    o.z = f2bf(v.z * nm); o.w = f2bf(v.w * nm);
    ((ushort4*)xb)[i] = o;
}

// ============ gathers (row-major, request-count-optimal) ============
// gather64: 1 node/wave, 4 edge-groups of 16 lanes (2 line-touches/edge).
__global__ __launch_bounds__(256) void gather64_kernel(const bf16_t* __restrict__ xb,
                                                       const int* __restrict__ rowptr,
                                                       const int* __restrict__ csr_src,
                                                       const float* __restrict__ ndst,
                                                       bf16_t* __restrict__ outb) {
    const int l = threadIdx.x & 63;
    const int q = l >> 4;                  // quarter 0..3
    const int s16 = l & 15;
    const int node = (blockIdx.x * 256 + threadIdx.x) >> 6;
    if (node >= N_NODES) return;
    const int r0 = rowptr[node], r1 = rowptr[node + 1];
    float a0 = 0.f, a1 = 0.f, a2 = 0.f, a3 = 0.f;
    for (int base = r0; base < r1; base += 16) {
        const int nb = min(16, r1 - base);
        int myidx = csr_src[base + min(s16, nb - 1)];
#pragma unroll
        for (int j = 0; j < 16; j += 4) {
            if (j >= nb) break;
            int e = j + q;
            int s = __shfl(myidx, min(e, nb - 1));
            if (e < nb) {
                ushort4 u = *(const ushort4*)(xb + (size_t)s * IN_FEATS + s16 * 4);
                a0 += bf2f(u.x); a1 += bf2f(u.y); a2 += bf2f(u.z); a3 += bf2f(u.w);
            }
        }
    }
    a0 += __shfl_xor(a0, 16); a1 += __shfl_xor(a1, 16);
    a2 += __shfl_xor(a2, 16); a3 += __shfl_xor(a3, 16);
    a0 += __shfl_xor(a0, 32); a1 += __shfl_xor(a1, 32);
    a2 += __shfl_xor(a2, 32); a3 += __shfl_xor(a3, 32);
    if (q == 0) {
        float nm = ndst[node];
        ushort4 o;
        o.x = f2bf(a0 * nm); o.y = f2bf(a1 * nm);
        o.z = f2bf(a2 * nm); o.w = f2bf(a3 * nm);
        *(ushort4*)(outb + (size_t)node * IN_FEATS + s16 * 4) = o;
    }
}

// gather128: 1 node/wave, 2 edge-halves of 32 lanes (4 line-touches/edge).
__global__ __launch_bounds__(256) void gather128_kernel(const bf16_t* __restrict__ hb,
                                                        const int* __restrict__ rowptr,
                                                        const int* __restrict__ csr_src,
                                                        const float* __restrict__ ndst,
                                                        bf16_t* __restrict__ outb) {
    const int l = threadIdx.x & 63;
    const int half = l >> 5;
    const int sub = l & 31;
    const int node = (blockIdx.x * 256 + threadIdx.x) >> 6;
    if (node >= N_NODES) return;
    const int r0 = rowptr[node], r1 = rowptr[node + 1];
    float a0 = 0.f, a1 = 0.f, a2 = 0.f, a3 = 0.f;
    for (int base = r0; base < r1; base += 32) {
        const int nb = min(32, r1 - base);
        int myidx = csr_src[base + min(sub, nb - 1)];
#pragma unroll 8
        for (int j = 0; j < nb; j += 2) {
            int e = j + half;
            int s = __shfl(myidx, min(e, nb - 1));
            if (e < nb) {
                ushort4 u = *(const ushort4*)(hb + (size_t)s * HIDDEN + sub * 4);
                a0 += bf2f(u.x); a1 += bf2f(u.y); a2 += bf2f(u.z); a3 += bf2f(u.w);
            }
        }
    }
    a0 += __shfl_xor(a0, 32); a1 += __shfl_xor(a1, 32);
    a2 += __shfl_xor(a2, 32); a3 += __shfl_xor(a3, 32);
    if (half == 0) {
        float nm = ndst[node];
        ushort4 o;
        o.x = f2bf(a0 * nm); o.y = f2bf(a1 * nm);
        o.z = f2bf(a2 * nm); o.w = f2bf(a3 * nm);
        *(ushort4*)(outb + (size_t)node * HIDDEN + sub * 4) = o;
    }
}

// ============ MFMA node matmul (row-major in/out, fused epilogue) ============
template <int K, bool SCALE_OUT>
__global__ __launch_bounds__(256) void node_matmul_mfma(const bf16_t* __restrict__ Hb,
                                                        const bf16_t* __restrict__ Wt,
                                                        const float* __restrict__ bias,
                                                        const float* __restrict__ nsrc,
                                                        bf16_t* __restrict__ outb) {
    __shared__ char sW[128 * K * 2];
    const int t = threadIdx.x;

    for (int fb = t * 16; fb < 128 * K * 2; fb += 256 * 16) {
        bfx8 v = *(const bfx8*)((const char*)Wt + fb);
        int n = fb / (2 * K);
        *(bfx8*)(sW + (fb ^ ((n & 7) << 4))) = v;
    }
    __syncthreads();

    const int wv = t >> 6;
    const int l  = t & 63;
    const int m  = l & 15;
    const int kb = l >> 4;
    const int row0 = blockIdx.x * 64 + wv * 16;

    int arow = row0 + m;
    if (arow > N_NODES - 1) arow = N_NODES - 1;
    const char* aptr = (const char*)(Hb + (size_t)arow * K);

    f32x4 acc[8];
#pragma unroll
    for (int f = 0; f < 8; ++f) acc[f] = (f32x4){0.f, 0.f, 0.f, 0.f};

#pragma unroll
    for (int kc = 0; kc < K / 32; ++kc) {
        bfx8 a = *(const bfx8*)(aptr + kc * 64 + kb * 16);
#pragma unroll
        for (int f = 0; f < 8; ++f) {
            int n = f * 16 + m;
            int off = n * (2 * K) + kc * 64 + kb * 16;
            off ^= (n & 7) << 4;
            bfx8 b = *(const bfx8*)(sW + off);
            acc[f] = __builtin_amdgcn_mfma_f32_16x16x32_bf16(a, b, acc[f], 0, 0, 0);
        }
    }

    int nodes[4];
    float nm[4];
#pragma unroll
    for (int j = 0; j < 4; ++j) {
        nodes[j] = row0 + kb * 4 + j;
        nm[j] = 1.f;
        if (SCALE_OUT && nodes[j] < N_NODES) nm[j] = nsrc[nodes[j]];
    }
#pragma unroll
    for (int f = 0; f < 8; ++f) {
        int feat = f * 16 + m;
        float bb = bias[feat];
#pragma unroll
        for (int j = 0; j < 4; ++j) {
            if (nodes[j] < N_NODES) {
                float v = selu_f(acc[f][j] + bb) * nm[j];
                outb[(size_t)nodes[j] * HIDDEN + feat] = f2bf(v);
            }
        }
    }
}

// ============ pool + MLP head ============
__global__ __launch_bounds__(256) void pool_kernel(const bf16_t* __restrict__ h,
                                                   const int* __restrict__ gid,
                                                   float* __restrict__ emb,
                                                   float* __restrict__ cnt) {
    const int lane = threadIdx.x & 63;
    const int wid = (blockIdx.x * 256 + threadIdx.x) >> 6;
    const int n0 = wid * 64;
    if (n0 >= N_NODES) return;
    const int nend = (n0 + 64 < N_NODES) ? n0 + 64 : N_NODES;
    int cur = gid[n0];
    float ax = 0.f, ay = 0.f, run = 0.f;
    for (int n = n0; n < nend; ++n) {
        int g = gid[n];
        if (g != cur) {
            atomicAdd(&emb[(size_t)cur * HIDDEN + lane * 2], ax);
            atomicAdd(&emb[(size_t)cur * HIDDEN + lane * 2 + 1], ay);
            if (lane == 0) atomicAdd(&cnt[cur], run);
            cur = g; ax = 0.f; ay = 0.f; run = 0.f;
        }
        ushort2 u = *(const ushort2*)(h + (size_t)n * HIDDEN + lane * 2);
        ax += bf2f(u.x); ay += bf2f(u.y);
        run += 1.f;
    }
    atomicAdd(&emb[(size_t)cur * HIDDEN + lane * 2], ax);
    atomicAdd(&emb[(size_t)cur * HIDDEN + lane * 2 + 1], ay);
    if (lane == 0) atomicAdd(&cnt[cur], run);
}

__global__ __launch_bounds__(256) void mlp_kernel(const float* __restrict__ emb,
                                                  const float* __restrict__ cnt,
                                                  const float* __restrict__ fg,
                                                  const float* __restrict__ M1, const float* __restrict__ c1,
                                                  const float* __restrict__ M2, const float* __restrict__ c2,
                                                  const float* __restrict__ M3, const float* __restrict__ c3,
                                                  float* __restrict__ out) {
    const int g = blockIdx.x;
    const int t = threadIdx.x;
    __shared__ float z[HIDDEN + EXTRA];
    __shared__ float z1[2 * HIDDEN];
    __shared__ float z2[HIDDEN];
    if (t < HIDDEN) {
        float c = fmaxf(cnt[g], 1.f);
        z[t] = emb[(size_t)g * HIDDEN + t] / c;
    } else if (t < HIDDEN + EXTRA) {
        z[t] = fg[g * EXTRA + (t - HIDDEN)];
    }
    __syncthreads();
    {
        float s = c1[t];
        for (int k = 0; k < HIDDEN + EXTRA; ++k) s += z[k] * M1[k * (2 * HIDDEN) + t];
        z1[t] = selu_f(s);
    }
    __syncthreads();
    if (t < HIDDEN) {
        float s = c2[t];
        for (int k = 0; k < 2 * HIDDEN; ++k) s += z1[k] * M2[k * HIDDEN + t];
        z2[t] = selu_f(s);
    }
    __syncthreads();
    if (t < 64) {
        float s = z2[t] * M3[t] + z2[t + 64] * M3[t + 64];
#pragma unroll
        for (int off = 32; off; off >>= 1) s += __shfl_down(s, off);
        if (t == 0) out[g] = s + c3[0];
    }
}

extern "C" void kernel_launch(void* const* d_in, const int* in_sizes, int n_in,
                              void* d_out, int out_size, void* d_ws, size_t ws_size,
                              hipStream_t stream) {
    const float* feats_node  = (const float*)d_in[0];
    const float* feats_graph = (const float*)d_in[1];
    const int*   src         = (const int*)d_in[2];
    const int*   dst         = (const int*)d_in[3];
    const int*   gid         = (const int*)d_in[4];
    const float* W1 = (const float*)d_in[5];
    const float* b1 = (const float*)d_in[6];
    const float* W2 = (const float*)d_in[7];
    const float* b2 = (const float*)d_in[8];
    const float* W3 = (const float*)d_in[9];
    const float* b3 = (const float*)d_in[10];
    const float* M1 = (const float*)d_in[11];
    const float* c1 = (const float*)d_in[12];
    const float* M2 = (const float*)d_in[13];
    const float* c2 = (const float*)d_in[14];
    const float* M3 = (const float*)d_in[15];
    const float* c3 = (const float*)d_in[16];
    float* out = (float*)d_out;

    char* ws = (char*)d_ws;
    int* indeg   = (int*)ws;  ws += (size_t)N_NODES * sizeof(int);
    int* outdeg  = (int*)ws;  ws += (size_t)N_NODES * sizeof(int);
    int* rowptr  = (int*)ws;  ws += (size_t)(N_NODES + 4) * sizeof(int);
    int* partials= (int*)ws;  ws += 128 * sizeof(int);
    float* norm_src = (float*)ws; ws += (size_t)N_NODES * sizeof(float);
    float* norm_dst = (float*)ws; ws += (size_t)N_NODES * sizeof(float);
    bf16_t* Wt1 = (bf16_t*)ws; ws += (size_t)128 * IN_FEATS * sizeof(bf16_t);
    bf16_t* Wt2 = (bf16_t*)ws; ws += (size_t)128 * HIDDEN * sizeof(bf16_t);
    bf16_t* Wt3 = (bf16_t*)ws; ws += (size_t)128 * HIDDEN * sizeof(bf16_t);
    int* csr_src = (int*)ws;  ws += (size_t)N_EDGES * sizeof(int);
    bf16_t* bufB = (bf16_t*)ws; ws += (size_t)N_NODES * HIDDEN * sizeof(bf16_t);
    // union 1: h_dst (alive histo..sortT) / bufA (alive after sortT)
    unsigned char* h_dst = (unsigned char*)ws;
    bf16_t* bufA = (bf16_t*)ws;
    ws += (size_t)G_SORT * N_NODES;                                  // 25.6 MB
    // union 2: h_src (alive histo..degs) / xb + emb + cnt
    unsigned char* h_src = (unsigned char*)ws;
    bf16_t* xb   = (bf16_t*)ws;
    float* emb   = (float*)(ws + (size_t)N_NODES * IN_FEATS * sizeof(bf16_t));
    float* cnt   = emb + (size_t)N_GRAPHS * HIDDEN;
    ws += (size_t)G_SORT * N_NODES;                                  // 25.6 MB

    // ---- CSR build (counting sort, no global atomics) ----
    histo_kernel<<<G_SORT, 512, 0, stream>>>(src, dst, h_src, h_dst);
    degs_kernel<<<(N_NODES + 255) / 256, 256, 0, stream>>>(h_src, h_dst, outdeg, indeg);
    scanA<<<NB_CHUNKS, 256, 0, stream>>>(indeg, partials);
    scanB<<<1, 128, 0, stream>>>(partials, rowptr);
    scanC<<<NB_CHUNKS, 256, 0, stream>>>(indeg, partials, rowptr);
    norm_kernel<<<(N_NODES + 255) / 256, 256, 0, stream>>>(outdeg, indeg, norm_src, norm_dst);
    sortT_kernel<<<G_SORT, 512, 0, stream>>>(src, dst, h_dst, rowptr, csr_src);

    // ---- weight prep + prescale (xb overlays h_src: dead after degs) ----
    wprep_kernel<<<(128 * IN_FEATS + 255) / 256, 256, 0, stream>>>(W1, Wt1, IN_FEATS);
    wprep_kernel<<<(128 * HIDDEN + 255) / 256, 256, 0, stream>>>(W2, Wt2, HIDDEN);
    wprep_kernel<<<(128 * HIDDEN + 255) / 256, 256, 0, stream>>>(W3, Wt3, HIDDEN);
    prescale_kernel<<<(N_NODES * (IN_FEATS / 4) + 255) / 256, 256, 0, stream>>>(feats_node, norm_src, xb);

    const int mm_grid = (N_NODES + 63) / 64;
    const int g_grid  = (N_NODES + 3) / 4;   // 1 node/wave, 4 waves/block

    // layer 1: aggregate(64) -> MFMA matmul(64->128) w/ selu+bias+nsrc epilogue
    gather64_kernel<<<g_grid, 256, 0, stream>>>(xb, rowptr, csr_src, norm_dst, bufA);
    node_matmul_mfma<IN_FEATS, true><<<mm_grid, 256, 0, stream>>>(bufA, Wt1, b1, norm_src, bufB);

    // layer 2
    gather128_kernel<<<g_grid, 256, 0, stream>>>(bufB, rowptr, csr_src, norm_dst, bufA);
    node_matmul_mfma<HIDDEN, true><<<mm_grid, 256, 0, stream>>>(bufA, Wt2, b2, norm_src, bufB);

    // layer 3 (no nsrc on output; feeds pooling)
    gather128_kernel<<<g_grid, 256, 0, stream>>>(bufB, rowptr, csr_src, norm_dst, bufA);
    node_matmul_mfma<HIDDEN, false><<<mm_grid, 256, 0, stream>>>(bufA, Wt3, b3, norm_src, bufB);

    // readout + MLP (emb/cnt overlay xb tail region; xb dead after layer 1)
    hipMemsetAsync(emb, 0, ((size_t)N_GRAPHS * HIDDEN + N_GRAPHS) * sizeof(float), stream);
    const int n_waves = (N_NODES + 63) / 64;
    pool_kernel<<<(n_waves + 3) / 4, 256, 0, stream>>>(bufB, gid, emb, cnt);
    mlp_kernel<<<N_GRAPHS, 256, 0, stream>>>(emb, cnt, feats_graph,
                                             M1, c1, M2, c2, M3, c3, out);
}

// Round 10
// 646.783 us; speedup vs baseline: 1.7506x; 1.0532x over previous
//
#include <hip/hip_runtime.h>
#include <hip/hip_bf16.h>
#include <cstddef>

#define N_NODES 100000
#define N_EDGES 3200000
#define N_GRAPHS 2048
#define IN_FEATS 64
#define HIDDEN 128
#define EXTRA 8

#define SCAN_CHUNK 1024
#define NB_CHUNKS ((N_NODES + SCAN_CHUNK - 1) / SCAN_CHUNK)  // 98

// counting-sort parameters: u8x4-packed LDS bins, 64000 bins/pass, 2 passes
#define R_BINS 64000
#define NPASS 2                      // 2 * 64000 >= 100000
#define G_SORT 256
#define CHUNK (N_EDGES / G_SORT)     // 12500

typedef unsigned short bf16_t;
typedef short bfx8 __attribute__((ext_vector_type(8)));
typedef float f32x4 __attribute__((ext_vector_type(4)));

__device__ __forceinline__ float selu_f(float x) {
    const float scale = 1.0507009873554805f;
    const float alpha = 1.6732632423543772f;
    return x > 0.f ? scale * x : scale * alpha * (__expf(x) - 1.f);
}
__device__ __forceinline__ float bf2f(unsigned short u) {
    union { unsigned int i; float f; } c; c.i = ((unsigned int)u) << 16; return c.f;
}
__device__ __forceinline__ unsigned short f2bf(float f) {
    union { float f; unsigned int i; } c; c.f = f;
    unsigned int lsb = (c.i >> 16) & 1;
    c.i += 0x7fffu + lsb;                 // round to nearest even
    return (unsigned short)(c.i >> 16);
}

// ============ counting-sort CSR build (no global atomics) ============
// u8x4-packed histogram: 64000 bins/pass in 16000 u32 words. Per-(block,bin)
// count <= ~8 (Poisson lambda 0.195) and per-bin rank <= indeg_max ~70 -> u8
// safe, no byte carry.

__global__ __launch_bounds__(512) void histo_kernel(const int* __restrict__ src,
                                                    const int* __restrict__ dst,
                                                    unsigned char* __restrict__ h_src,
                                                    unsigned char* __restrict__ h_dst) {
    __shared__ unsigned int hist[R_BINS / 4];   // 16000 words, 64000 B
    const int b = blockIdx.x, t = threadIdx.x;
    const int e0 = b * CHUNK;
#pragma unroll
    for (int ph = 0; ph < 2; ++ph) {
        const int4* key4 = (const int4*)((ph ? src : dst) + e0);
        unsigned char* hout = (ph ? h_src : h_dst) + (size_t)b * N_NODES;
        for (int p = 0; p < NPASS; ++p) {
            const int r0 = p * R_BINS;
            const int rend = min(R_BINS, N_NODES - r0);   // 64000 / 36000, both %4==0
            for (int i = t; i < R_BINS / 4; i += 512) hist[i] = 0;
            __syncthreads();
            for (int i = t; i < CHUNK / 4; i += 512) {
                int4 k = key4[i];
                unsigned int x;
                x = (unsigned)(k.x - r0); if (x < (unsigned)R_BINS) atomicAdd(&hist[x >> 2], 1u << ((x & 3) << 3));
                x = (unsigned)(k.y - r0); if (x < (unsigned)R_BINS) atomicAdd(&hist[x >> 2], 1u << ((x & 3) << 3));
                x = (unsigned)(k.z - r0); if (x < (unsigned)R_BINS) atomicAdd(&hist[x >> 2], 1u << ((x & 3) << 3));
                x = (unsigned)(k.w - r0); if (x < (unsigned)R_BINS) atomicAdd(&hist[x >> 2], 1u << ((x & 3) << 3));
            }
            __syncthreads();
            unsigned int* ho4 = (unsigned int*)(hout + r0);
            for (int i = t; i < rend / 4; i += 512) ho4[i] = hist[i];
            __syncthreads();
        }
    }
}

// merged: outdeg/nsrc = colsum(h_src); h_dst -> in-place per-bin block prefix;
// indeg/ndst = total
__global__ __launch_bounds__(256) void degs_kernel(const unsigned char* __restrict__ h_src,
                                                   unsigned char* __restrict__ h_dst,
                                                   int* __restrict__ indeg,
                                                   float* __restrict__ nsrc,
                                                   float* __restrict__ ndst) {
    int bin = blockIdx.x * 256 + threadIdx.x;
    if (bin >= N_NODES) return;
    int s = 0;
#pragma unroll 8
    for (int b = 0; b < G_SORT; ++b) s += h_src[(size_t)b * N_NODES + bin];
    nsrc[bin] = rsqrtf(fmaxf((float)s, 1.f));
    int run = 0;
#pragma unroll 8
    for (int b = 0; b < G_SORT; ++b) {
        size_t off = (size_t)b * N_NODES + bin;
        int v = h_dst[off];
        h_dst[off] = (unsigned char)run;
        run += v;
    }
    indeg[bin] = run;
    ndst[bin] = rsqrtf(fmaxf((float)run, 1.f));
}

// 2-pass scatter: rank from u8x4-packed LDS counters; slot = rowptr[d] + rank
__global__ __launch_bounds__(512) void sortT_kernel(const int* __restrict__ src,
                                                    const int* __restrict__ dst,
                                                    const unsigned char* __restrict__ h_dst,
                                                    const int* __restrict__ rowptr,
                                                    int* __restrict__ csr_src) {
    __shared__ unsigned int cnt[R_BINS / 4];   // 16000 words
    const int b = blockIdx.x, t = threadIdx.x;
    const int e0 = b * CHUNK;
    const int4* d4p = (const int4*)(dst + e0);
    const int4* s4p = (const int4*)(src + e0);
    const unsigned char* hrow = h_dst + (size_t)b * N_NODES;
    for (int p = 0; p < NPASS; ++p) {
        const int r0 = p * R_BINS;
        const int rend = min(R_BINS, N_NODES - r0);
        const unsigned int* hr4 = (const unsigned int*)(hrow + r0);
        for (int i = t; i < rend / 4; i += 512) cnt[i] = hr4[i];
        __syncthreads();
        for (int i = t; i < CHUNK / 4; i += 512) {
            int4 d = d4p[i];
            int4 s = s4p[i];
            unsigned int x, old, rank;
            x = (unsigned)(d.x - r0);
            if (x < (unsigned)R_BINS) {
                old = atomicAdd(&cnt[x >> 2], 1u << ((x & 3) << 3));
                rank = (old >> ((x & 3) << 3)) & 0xffu;
                csr_src[rowptr[d.x] + rank] = s.x;
            }
            x = (unsigned)(d.y - r0);
            if (x < (unsigned)R_BINS) {
                old = atomicAdd(&cnt[x >> 2], 1u << ((x & 3) << 3));
                rank = (old >> ((x & 3) << 3)) & 0xffu;
                csr_src[rowptr[d.y] + rank] = s.y;
            }
            x = (unsigned)(d.z - r0);
            if (x < (unsigned)R_BINS) {
                old = atomicAdd(&cnt[x >> 2], 1u << ((x & 3) << 3));
                rank = (old >> ((x & 3) << 3)) & 0xffu;
                csr_src[rowptr[d.z] + rank] = s.z;
            }
            x = (unsigned)(d.w - r0);
            if (x < (unsigned)R_BINS) {
                old = atomicAdd(&cnt[x >> 2], 1u << ((x & 3) << 3));
                rank = (old >> ((x & 3) << 3)) & 0xffu;
                csr_src[rowptr[d.w] + rank] = s.w;
            }
        }
        __syncthreads();
    }
}

// ============ rowptr scan, weights, features ============

__global__ __launch_bounds__(256) void scanA(const int* __restrict__ indeg,
                                             int* __restrict__ partials) {
    __shared__ int red[4];
    const int b = blockIdx.x, t = threadIdx.x;
    int base = b * SCAN_CHUNK + t * 4;
    int s = 0;
#pragma unroll
    for (int k = 0; k < 4; ++k) { int i = base + k; if (i < N_NODES) s += indeg[i]; }
    for (int off = 32; off; off >>= 1) s += __shfl_down(s, off);
    if ((t & 63) == 0) red[t >> 6] = s;
    __syncthreads();
    if (t == 0) partials[b] = red[0] + red[1] + red[2] + red[3];
}

__global__ __launch_bounds__(128) void scanB(int* __restrict__ partials,
                                             int* __restrict__ rowptr) {
    __shared__ int s[128];
    const int t = threadIdx.x;
    int v = (t < NB_CHUNKS) ? partials[t] : 0;
    s[t] = v;
    __syncthreads();
    for (int off = 1; off < 128; off <<= 1) {
        int u = (t >= off) ? s[t - off] : 0;
        __syncthreads();
        s[t] += u;
        __syncthreads();
    }
    if (t < NB_CHUNKS) partials[t] = s[t] - v;   // exclusive
    if (t == 127) rowptr[N_NODES] = s[127];
}

__global__ __launch_bounds__(256) void scanC(const int* __restrict__ indeg,
                                             const int* __restrict__ partials,
                                             int* __restrict__ rowptr) {
    __shared__ int ts[256];
    const int b = blockIdx.x, t = threadIdx.x;
    int base = b * SCAN_CHUNK + t * 4;
    int v[4];
    int s = 0;
#pragma unroll
    for (int k = 0; k < 4; ++k) { int i = base + k; v[k] = (i < N_NODES) ? indeg[i] : 0; s += v[k]; }
    ts[t] = s;
    __syncthreads();
    for (int off = 1; off < 256; off <<= 1) {
        int u = (t >= off) ? ts[t - off] : 0;
        __syncthreads();
        ts[t] += u;
        __syncthreads();
    }
    int excl = ts[t] - s + partials[b];
#pragma unroll
    for (int k = 0; k < 4; ++k) {
        int i = base + k;
        if (i < N_NODES) rowptr[i] = excl;
        excl += v[k];
    }
}

__global__ __launch_bounds__(256) void wprep_kernel(const float* __restrict__ W,
                                                    bf16_t* __restrict__ Wt, int K) {
    int i = blockIdx.x * 256 + threadIdx.x;
    if (i >= 128 * K) return;
    int n = i / K, k = i - n * K;
    Wt[i] = f2bf(W[k * 128 + n]);
}

__global__ __launch_bounds__(256) void prescale_kernel(const float* __restrict__ x,
                                                       const float* __restrict__ nsrc,
                                                       bf16_t* __restrict__ xb) {
    int i = blockIdx.x * 256 + threadIdx.x;
    const int total = N_NODES * (IN_FEATS / 4);
    if (i >= total) return;
    int node = i >> 4;                       // IN_FEATS/4 == 16
    float nm = nsrc[node];
    float4 v = ((const float4*)x)[i];
    ushort4 o;
    o.x = f2bf(v.x * nm); o.y = f2bf(v.y * nm);
    o.z = f2bf(v.z * nm); o.w = f2bf(v.w * nm);
    ((ushort4*)xb)[i] = o;
}

// ============ gathers (row-major, request-count-optimal; NT csr stream) ============
__global__ __launch_bounds__(256) void gather64_kernel(const bf16_t* __restrict__ xb,
                                                       const int* __restrict__ rowptr,
                                                       const int* __restrict__ csr_src,
                                                       const float* __restrict__ ndst,
                                                       bf16_t* __restrict__ outb) {
    const int l = threadIdx.x & 63;
    const int q = l >> 4;                  // quarter 0..3
    const int s16 = l & 15;
    const int node = (blockIdx.x * 256 + threadIdx.x) >> 6;
    if (node >= N_NODES) return;
    const int r0 = rowptr[node], r1 = rowptr[node + 1];
    float a0 = 0.f, a1 = 0.f, a2 = 0.f, a3 = 0.f;
    for (int base = r0; base < r1; base += 16) {
        const int nb = min(16, r1 - base);
        int myidx = __builtin_nontemporal_load(&csr_src[base + min(s16, nb - 1)]);
#pragma unroll
        for (int j = 0; j < 16; j += 4) {
            if (j >= nb) break;
            int e = j + q;
            int s = __shfl(myidx, min(e, nb - 1));
            if (e < nb) {
                ushort4 u = *(const ushort4*)(xb + (size_t)s * IN_FEATS + s16 * 4);
                a0 += bf2f(u.x); a1 += bf2f(u.y); a2 += bf2f(u.z); a3 += bf2f(u.w);
            }
        }
    }
    a0 += __shfl_xor(a0, 16); a1 += __shfl_xor(a1, 16);
    a2 += __shfl_xor(a2, 16); a3 += __shfl_xor(a3, 16);
    a0 += __shfl_xor(a0, 32); a1 += __shfl_xor(a1, 32);
    a2 += __shfl_xor(a2, 32); a3 += __shfl_xor(a3, 32);
    if (q == 0) {
        float nm = ndst[node];
        ushort4 o;
        o.x = f2bf(a0 * nm); o.y = f2bf(a1 * nm);
        o.z = f2bf(a2 * nm); o.w = f2bf(a3 * nm);
        *(ushort4*)(outb + (size_t)node * IN_FEATS + s16 * 4) = o;
    }
}

__global__ __launch_bounds__(256) void gather128_kernel(const bf16_t* __restrict__ hb,
                                                        const int* __restrict__ rowptr,
                                                        const int* __restrict__ csr_src,
                                                        const float* __restrict__ ndst,
                                                        bf16_t* __restrict__ outb) {
    const int l = threadIdx.x & 63;
    const int half = l >> 5;
    const int sub = l & 31;
    const int node = (blockIdx.x * 256 + threadIdx.x) >> 6;
    if (node >= N_NODES) return;
    const int r0 = rowptr[node], r1 = rowptr[node + 1];
    float a0 = 0.f, a1 = 0.f, a2 = 0.f, a3 = 0.f;
    for (int base = r0; base < r1; base += 32) {
        const int nb = min(32, r1 - base);
        int myidx = __builtin_nontemporal_load(&csr_src[base + min(sub, nb - 1)]);
#pragma unroll 8
        for (int j = 0; j < nb; j += 2) {
            int e = j + half;
            int s = __shfl(myidx, min(e, nb - 1));
            if (e < nb) {
                ushort4 u = *(const ushort4*)(hb + (size_t)s * HIDDEN + sub * 4);
                a0 += bf2f(u.x); a1 += bf2f(u.y); a2 += bf2f(u.z); a3 += bf2f(u.w);
            }
        }
    }
    a0 += __shfl_xor(a0, 32); a1 += __shfl_xor(a1, 32);
    a2 += __shfl_xor(a2, 32); a3 += __shfl_xor(a3, 32);
    if (half == 0) {
        float nm = ndst[node];
        ushort4 o;
        o.x = f2bf(a0 * nm); o.y = f2bf(a1 * nm);
        o.z = f2bf(a2 * nm); o.w = f2bf(a3 * nm);
        *(ushort4*)(outb + (size_t)node * HIDDEN + sub * 4) = o;
    }
}

// ============ MFMA node matmul (row-major in/out, fused epilogue) ============
template <int K, bool SCALE_OUT>
__global__ __launch_bounds__(256) void node_matmul_mfma(const bf16_t* __restrict__ Hb,
                                                        const bf16_t* __restrict__ Wt,
                                                        const float* __restrict__ bias,
                                                        const float* __restrict__ nsrc,
                                                        bf16_t* __restrict__ outb) {
    __shared__ char sW[128 * K * 2];
    const int t = threadIdx.x;

    for (int fb = t * 16; fb < 128 * K * 2; fb += 256 * 16) {
        bfx8 v = *(const bfx8*)((const char*)Wt + fb);
        int n = fb / (2 * K);
        *(bfx8*)(sW + (fb ^ ((n & 7) << 4))) = v;
    }
    __syncthreads();

    const int wv = t >> 6;
    const int l  = t & 63;
    const int m  = l & 15;
    const int kb = l >> 4;
    const int row0 = blockIdx.x * 64 + wv * 16;

    int arow = row0 + m;
    if (arow > N_NODES - 1) arow = N_NODES - 1;
    const char* aptr = (const char*)(Hb + (size_t)arow * K);

    f32x4 acc[8];
#pragma unroll
    for (int f = 0; f < 8; ++f) acc[f] = (f32x4){0.f, 0.f, 0.f, 0.f};

#pragma unroll
    for (int kc = 0; kc < K / 32; ++kc) {
        bfx8 a = *(const bfx8*)(aptr + kc * 64 + kb * 16);
#pragma unroll
        for (int f = 0; f < 8; ++f) {
            int n = f * 16 + m;
            int off = n * (2 * K) + kc * 64 + kb * 16;
            off ^= (n & 7) << 4;
            bfx8 b = *(const bfx8*)(sW + off);
            acc[f] = __builtin_amdgcn_mfma_f32_16x16x32_bf16(a, b, acc[f], 0, 0, 0);
        }
    }

    int nodes[4];
    float nm[4];
#pragma unroll
    for (int j = 0; j < 4; ++j) {
        nodes[j] = row0 + kb * 4 + j;
        nm[j] = 1.f;
        if (SCALE_OUT && nodes[j] < N_NODES) nm[j] = nsrc[nodes[j]];
    }
#pragma unroll
    for (int f = 0; f < 8; ++f) {
        int feat = f * 16 + m;
        float bb = bias[feat];
#pragma unroll
        for (int j = 0; j < 4; ++j) {
            if (nodes[j] < N_NODES) {
                float v = selu_f(acc[f][j] + bb) * nm[j];
                outb[(size_t)nodes[j] * HIDDEN + feat] = f2bf(v);
            }
        }
    }
}

// ============ pool + MLP head ============
__global__ __launch_bounds__(256) void pool_kernel(const bf16_t* __restrict__ h,
                                                   const int* __restrict__ gid,
                                                   float* __restrict__ emb,
                                                   float* __restrict__ cnt) {
    const int lane = threadIdx.x & 63;
    const int wid = (blockIdx.x * 256 + threadIdx.x) >> 6;
    const int n0 = wid * 64;
    if (n0 >= N_NODES) return;
    const int nend = (n0 + 64 < N_NODES) ? n0 + 64 : N_NODES;
    int cur = gid[n0];
    float ax = 0.f, ay = 0.f, run = 0.f;
    for (int n = n0; n < nend; ++n) {
        int g = gid[n];
        if (g != cur) {
            atomicAdd(&emb[(size_t)cur * HIDDEN + lane * 2], ax);
            atomicAdd(&emb[(size_t)cur * HIDDEN + lane * 2 + 1], ay);
            if (lane == 0) atomicAdd(&cnt[cur], run);
            cur = g; ax = 0.f; ay = 0.f; run = 0.f;
        }
        ushort2 u = *(const ushort2*)(h + (size_t)n * HIDDEN + lane * 2);
        ax += bf2f(u.x); ay += bf2f(u.y);
        run += 1.f;
    }
    atomicAdd(&emb[(size_t)cur * HIDDEN + lane * 2], ax);
    atomicAdd(&emb[(size_t)cur * HIDDEN + lane * 2 + 1], ay);
    if (lane == 0) atomicAdd(&cnt[cur], run);
}

__global__ __launch_bounds__(256) void mlp_kernel(const float* __restrict__ emb,
                                                  const float* __restrict__ cnt,
                                                  const float* __restrict__ fg,
                                                  const float* __restrict__ M1, const float* __restrict__ c1,
                                                  const float* __restrict__ M2, const float* __restrict__ c2,
                                                  const float* __restrict__ M3, const float* __restrict__ c3,
                                                  float* __restrict__ out) {
    const int g = blockIdx.x;
    const int t = threadIdx.x;
    __shared__ float z[HIDDEN + EXTRA];
    __shared__ float z1[2 * HIDDEN];
    __shared__ float z2[HIDDEN];
    if (t < HIDDEN) {
        float c = fmaxf(cnt[g], 1.f);
        z[t] = emb[(size_t)g * HIDDEN + t] / c;
    } else if (t < HIDDEN + EXTRA) {
        z[t] = fg[g * EXTRA + (t - HIDDEN)];
    }
    __syncthreads();
    {
        float s = c1[t];
        for (int k = 0; k < HIDDEN + EXTRA; ++k) s += z[k] * M1[k * (2 * HIDDEN) + t];
        z1[t] = selu_f(s);
    }
    __syncthreads();
    if (t < HIDDEN) {
        float s = c2[t];
        for (int k = 0; k < 2 * HIDDEN; ++k) s += z1[k] * M2[k * HIDDEN + t];
        z2[t] = selu_f(s);
    }
    __syncthreads();
    if (t < 64) {
        float s = z2[t] * M3[t] + z2[t + 64] * M3[t + 64];
#pragma unroll
        for (int off = 32; off; off >>= 1) s += __shfl_down(s, off);
        if (t == 0) out[g] = s + c3[0];
    }
}

extern "C" void kernel_launch(void* const* d_in, const int* in_sizes, int n_in,
                              void* d_out, int out_size, void* d_ws, size_t ws_size,
                              hipStream_t stream) {
    const float* feats_node  = (const float*)d_in[0];
    const float* feats_graph = (const float*)d_in[1];
    const int*   src         = (const int*)d_in[2];
    const int*   dst         = (const int*)d_in[3];
    const int*   gid         = (const int*)d_in[4];
    const float* W1 = (const float*)d_in[5];
    const float* b1 = (const float*)d_in[6];
    const float* W2 = (const float*)d_in[7];
    const float* b2 = (const float*)d_in[8];
    const float* W3 = (const float*)d_in[9];
    const float* b3 = (const float*)d_in[10];
    const float* M1 = (const float*)d_in[11];
    const float* c1 = (const float*)d_in[12];
    const float* M2 = (const float*)d_in[13];
    const float* c2 = (const float*)d_in[14];
    const float* M3 = (const float*)d_in[15];
    const float* c3 = (const float*)d_in[16];
    float* out = (float*)d_out;

    char* ws = (char*)d_ws;
    int* indeg   = (int*)ws;  ws += (size_t)N_NODES * sizeof(int);
    int* rowptr  = (int*)ws;  ws += (size_t)(N_NODES + 4) * sizeof(int);
    int* partials= (int*)ws;  ws += 128 * sizeof(int);
    float* norm_src = (float*)ws; ws += (size_t)N_NODES * sizeof(float);
    float* norm_dst = (float*)ws; ws += (size_t)N_NODES * sizeof(float);
    bf16_t* Wt1 = (bf16_t*)ws; ws += (size_t)128 * IN_FEATS * sizeof(bf16_t);
    bf16_t* Wt2 = (bf16_t*)ws; ws += (size_t)128 * HIDDEN * sizeof(bf16_t);
    bf16_t* Wt3 = (bf16_t*)ws; ws += (size_t)128 * HIDDEN * sizeof(bf16_t);
    int* csr_src = (int*)ws;  ws += (size_t)N_EDGES * sizeof(int);
    bf16_t* bufB = (bf16_t*)ws; ws += (size_t)N_NODES * HIDDEN * sizeof(bf16_t);
    // union 1: h_dst (alive histo..sortT) / bufA (alive after sortT)
    unsigned char* h_dst = (unsigned char*)ws;
    bf16_t* bufA = (bf16_t*)ws;
    ws += (size_t)G_SORT * N_NODES;                                  // 25.6 MB
    // union 2: h_src (alive histo..degs) / xb + emb + cnt
    unsigned char* h_src = (unsigned char*)ws;
    bf16_t* xb   = (bf16_t*)ws;
    float* emb   = (float*)(ws + (size_t)N_NODES * IN_FEATS * sizeof(bf16_t));
    float* cnt   = emb + (size_t)N_GRAPHS * HIDDEN;
    ws += (size_t)G_SORT * N_NODES;                                  // 25.6 MB

    // ---- CSR build (counting sort, no global atomics) ----
    histo_kernel<<<G_SORT, 512, 0, stream>>>(src, dst, h_src, h_dst);
    degs_kernel<<<(N_NODES + 255) / 256, 256, 0, stream>>>(h_src, h_dst, indeg, norm_src, norm_dst);
    scanA<<<NB_CHUNKS, 256, 0, stream>>>(indeg, partials);
    scanB<<<1, 128, 0, stream>>>(partials, rowptr);
    scanC<<<NB_CHUNKS, 256, 0, stream>>>(indeg, partials, rowptr);
    sortT_kernel<<<G_SORT, 512, 0, stream>>>(src, dst, h_dst, rowptr, csr_src);

    // ---- weight prep + prescale (xb overlays h_src: dead after degs) ----
    wprep_kernel<<<(128 * IN_FEATS + 255) / 256, 256, 0, stream>>>(W1, Wt1, IN_FEATS);
    wprep_kernel<<<(128 * HIDDEN + 255) / 256, 256, 0, stream>>>(W2, Wt2, HIDDEN);
    wprep_kernel<<<(128 * HIDDEN + 255) / 256, 256, 0, stream>>>(W3, Wt3, HIDDEN);
    prescale_kernel<<<(N_NODES * (IN_FEATS / 4) + 255) / 256, 256, 0, stream>>>(feats_node, norm_src, xb);

    const int mm_grid = (N_NODES + 63) / 64;
    const int g_grid  = (N_NODES + 3) / 4;   // 1 node/wave, 4 waves/block

    // layer 1: aggregate(64) -> MFMA matmul(64->128) w/ selu+bias+nsrc epilogue
    gather64_kernel<<<g_grid, 256, 0, stream>>>(xb, rowptr, csr_src, norm_dst, bufA);
    node_matmul_mfma<IN_FEATS, true><<<mm_grid, 256, 0, stream>>>(bufA, Wt1, b1, norm_src, bufB);

    // layer 2
    gather128_kernel<<<g_grid, 256, 0, stream>>>(bufB, rowptr, csr_src, norm_dst, bufA);
    node_matmul_mfma<HIDDEN, true><<<mm_grid, 256, 0, stream>>>(bufA, Wt2, b2, norm_src, bufB);

    // layer 3 (no nsrc on output; feeds pooling)
    gather128_kernel<<<g_grid, 256, 0, stream>>>(bufB, rowptr, csr_src, norm_dst, bufA);
    node_matmul_mfma<HIDDEN, false><<<mm_grid, 256, 0, stream>>>(bufA, Wt3, b3, norm_src, bufB);

    // readout + MLP (emb/cnt overlay xb tail region; xb dead after layer 1)
    hipMemsetAsync(emb, 0, ((size_t)N_GRAPHS * HIDDEN + N_GRAPHS) * sizeof(float), stream);
    const int n_waves = (N_NODES + 63) / 64;
    pool_kernel<<<(n_waves + 3) / 4, 256, 0, stream>>>(bufB, gid, emb, cnt);
    mlp_kernel<<<N_GRAPHS, 256, 0, stream>>>(emb, cnt, feats_graph,
                                             M1, c1, M2, c2, M3, c3, out);
}